// Round 7
// baseline (502.210 us; speedup 1.0000x reference)
//
#include <hip/hip_runtime.h>
#include <math.h>

// Problem constants
#define NB 8
#define NT 2048
#define NC 128
#define NLM 64
#define NS 4
#define QROWS 2049
#define NCH 32  // 2048 / 64 chunks

#define TWO_LOG2E 2.885390081777927f

__device__ __forceinline__ float rcp_fast(float x) {
  return __builtin_amdgcn_rcpf(x);
}

__device__ __forceinline__ float readlane_f(float v, int lane) {
  return __int_as_float(__builtin_amdgcn_readlane(__float_as_int(v), lane));
}

// ---------------------------------------------------------------------------
// Tiled 64-step local linear scan (forward substitution); all indices
// compile-time so q[4][16] stays in VGPRs.
// ---------------------------------------------------------------------------
template <typename PF, typename DF>
__device__ __forceinline__ void tri_scan64(PF P, DF D, float q[4][16]) {
#pragma unroll
  for (int tau = 0; tau < 4; ++tau) {
    float acc[16];
#pragma unroll
    for (int i = 0; i < 16; ++i) acc[i] = D(tau * 16 + i);
#pragma unroll
    for (int p = 0; p < 4; ++p) {
      if (p < tau) {
#pragma unroll
        for (int i = 0; i < 16; ++i) {
          const int t = tau * 16 + i;
#pragma unroll
          for (int i2 = 0; i2 < 16; ++i2) {
            acc[i] = fmaf(P(t, t - (p * 16 + i2) - 1), q[p][i2], acc[i]);
          }
        }
      }
    }
#pragma unroll
    for (int i = 0; i < 16; ++i) {
      const int t = tau * 16 + i;
#pragma unroll
      for (int i2 = 0; i2 < 16; ++i2) {
        if (i2 < i) acc[i] = fmaf(P(t, i - i2 - 1), q[tau][i2], acc[i]);
      }
      q[tau][i] = acc[i];
    }
  }
}

// K1: per 8 rows (b,t): z = x@W + b ; u = [cos,sin]/sqrt(dh) ; V = u @ phi_w
__global__ __launch_bounds__(128) void k1_uv(
    const float* __restrict__ x, const float* __restrict__ W,
    const float* __restrict__ bias, const float* __restrict__ phiw,
    float* __restrict__ Q) {
  __shared__ float xs[8][128];
  __shared__ float us[8][256];
  const int j = threadIdx.x;
  const int bt0 = blockIdx.x * 8;
#pragma unroll
  for (int r = 0; r < 8; ++r) xs[r][j] = x[(bt0 + r) * NC + j];
  __syncthreads();
  float z[8];
  const float bj = bias[j];
#pragma unroll
  for (int r = 0; r < 8; ++r) z[r] = bj;
  for (int k = 0; k < 128; ++k) {
    float w = W[k * 128 + j];
#pragma unroll
    for (int r = 0; r < 8; ++r) z[r] = fmaf(xs[r][k], w, z[r]);
  }
  const float rs = 0.08838834764831845f;  // 1/sqrt(128)
#pragma unroll
  for (int r = 0; r < 8; ++r) {
    float sv, cv;
    sincosf(z[r], &sv, &cv);
    us[r][j] = cv * rs;
    us[r][128 + j] = sv * rs;
  }
  __syncthreads();
  float a[8];
#pragma unroll
  for (int r = 0; r < 8; ++r) a[r] = 0.f;
  for (int k = 0; k < 256; ++k) {
    float w = phiw[k * 128 + j];
#pragma unroll
    for (int r = 0; r < 8; ++r) a[r] = fmaf(us[r][k], w, a[r]);
  }
#pragma unroll
  for (int r = 0; r < 8; ++r) {
    int bt = bt0 + r;
    int b = bt >> 11, t = bt & 2047;
    Q[(b * QROWS + t + 1) * NC + j] = a[r];
  }
}

// K2a: per-chunk raw sums
__global__ __launch_bounds__(128) void k2a_sums(const float* __restrict__ Q,
                                                float* __restrict__ S2) {
  const int b = blockIdx.x, ch = blockIdx.y, c = threadIdx.x;
  float acc = 0.f;
#pragma unroll 8
  for (int i = 0; i < 64; ++i) acc += Q[(b * QROWS + ch * 64 + 1 + i) * NC + c];
  S2[(b * NCH + ch) * NC + c] = acc;
}

// K2c: each block sums its own exclusive prefix over raw chunk sums (<=31
// loads, independent -> pipelined), then fixes up its chunk. k2b eliminated.
__global__ __launch_bounds__(128) void k2c_fix(float* __restrict__ Q,
                                               const float* __restrict__ S2) {
  const int b = blockIdx.x, ch = blockIdx.y, c = threadIdx.x;
  if (ch == 0) Q[(b * QROWS) * NC + c] = 0.f;
  float run = 0.f;
  for (int i = 0; i < ch; ++i) run += S2[(b * NCH + i) * NC + c];
#pragma unroll 4
  for (int i = 0; i < 64; ++i) {
    float* p = Q + (b * QROWS + ch * 64 + 1 + i) * NC + c;
    run += *p;
    *p = run;
  }
}

// K3ab fused: unit-response matrix mT of the Z recurrence (LDS) + 32
// sequential chunk-steps of the rescaled linear logZ evolution. Per s.
__global__ __launch_bounds__(64) void k3ab_logz(const float* __restrict__ logw,
                                                float* __restrict__ logZt) {
  const int s = blockIdx.x;
  const int j = threadIdx.x;  // doubles as t in phase 2
  __shared__ float wx[64];
  __shared__ float mTs[64][65];  // [j][t], padded (writes are row-per-lane)
  __shared__ float Zr[64];
  wx[j] = __expf(logw[s * NLM + j]);
  __syncthreads();
  float q[4][16];
  tri_scan64([&](int t, int l) { return wx[l]; },
             [&](int t) { int l = t + j; return (l < 64) ? wx[l] : 0.f; }, q);
#pragma unroll
  for (int tau = 0; tau < 4; ++tau)
#pragma unroll
    for (int i = 0; i < 16; ++i) mTs[j][tau * 16 + i] = q[tau][i];
  // phase 2
  const int t = j;
  Zr[t] = (t == 0) ? 1.f : 0.f;
  if (t == 0) logZt[s * QROWS] = 0.f;
  float off = 0.f;
  __syncthreads();
  for (int ch = 0; ch < NCH; ++ch) {
    float acc = 0.f;
#pragma unroll 8
    for (int jj = 0; jj < 64; ++jj) acc = fmaf(mTs[jj][t], Zr[jj], acc);
    logZt[s * QROWS + ch * 64 + 1 + t] = logf(acc) + off;
    float mx = acc;
#pragma unroll
    for (int o = 32; o; o >>= 1) mx = fmaxf(mx, __shfl_xor(mx, o));
    __syncthreads();
    Zr[63 - t] = acc / mx;
    off += logf(mx);
    __syncthreads();
  }
}

// K5a-basis (per s,ch), now also computes pi for its chunk in-LDS (k3c fused):
// phase 0: pi[tt][l] = softmax_l(lw[l] + logZ[ti-l]) from a 128-wide logZ
//          window; written to LDS psd + global pi (for k4).
// phase 1: threads 0..63: impulse-response columns R (rt, [tp][t]);
//          threads 64..127: history responses ctT ([t][j]); klocal = rowsum R.
__global__ __launch_bounds__(128) void k5a_basis(const float* __restrict__ logw,
                                                 const float* __restrict__ logZt,
                                                 float* __restrict__ pig,
                                                 float* __restrict__ rt,
                                                 float* __restrict__ ctT,
                                                 float* __restrict__ klocal) {
  __shared__ __align__(16) float psd[4096];
  __shared__ float Rl[64][65];
  __shared__ float lzs[128];
  __shared__ float lws[64];
  const int s = blockIdx.x, ch = blockIdx.y;
  const int tid = threadIdx.x;
  {
    int idx = ch * 64 - 63 + tid;
    lzs[tid] = (idx >= 0) ? logZt[s * QROWS + idx] : -INFINITY;
    if (tid < 64) lws[tid] = logw[s * NLM + tid];
  }
  __syncthreads();
  {
    const int l = tid & 63, wv = tid >> 6;
    for (int tt = wv; tt < 64; tt += 2) {
      float la = lws[l] + lzs[tt + 63 - l];
      float m = la;
#pragma unroll
      for (int o = 32; o; o >>= 1) m = fmaxf(m, __shfl_xor(m, o));
      float p = __expf(la - m);
      float zs = p;
#pragma unroll
      for (int o = 32; o; o >>= 1) zs += __shfl_xor(zs, o);
      float pv = p * rcp_fast(zs);
      psd[tt * 64 + l] = pv;
      pig[((long)s * NT + ch * 64 + tt) * NLM + l] = pv;
    }
  }
  __syncthreads();
  float q[4][16];
  if (tid < 64) {
    const int tp = tid;  // impulse position
    tri_scan64([&](int t, int l) { return psd[t * 64 + l]; },
               [&](int t) { return (t == tp) ? 1.f : 0.f; }, q);
    float* rrow = rt + (((long)s * NCH + ch) * 64 + tp) * 64;  // [tp][t]
#pragma unroll
    for (int tau = 0; tau < 4; ++tau)
#pragma unroll
      for (int i = 0; i < 16; ++i) {
        rrow[tau * 16 + i] = q[tau][i];
        Rl[tp][tau * 16 + i] = q[tau][i];
      }
  } else {
    const int j = tid - 64;  // history lookback j+1
    tri_scan64([&](int t, int l) { return psd[t * 64 + l]; },
               [&](int t) { int l = t + j; return (l < 64) ? psd[t * 64 + l] : 0.f; }, q);
    float* ctb = ctT + ((long)s * NCH + ch) * 4096;  // [t][j]
#pragma unroll
    for (int tau = 0; tau < 4; ++tau)
#pragma unroll
      for (int i = 0; i < 16; ++i) ctb[(tau * 16 + i) * 64 + j] = q[tau][i];
  }
  __syncthreads();
  if (tid < 64) {  // klocal[t] = sum_t' R[t][t']
    float acc = 0.f;
#pragma unroll 8
    for (int tp = 0; tp < 64; ++tp) acc += Rl[tp][tid];
    klocal[((long)s * NCH + ch) * 64 + tid] = acc;
  }
}

// K4: e[s,b,ti,c] = 1 - 2 * sum_l pi[s,ti,l] * rcp(exp2(y)+1)
// 16-row tiles: LDS 20+16=36 KB -> 4 blocks/CU (was 56 KB -> 2).
__global__ __launch_bounds__(256) void k4_e(
    const float* __restrict__ Q, const float* __restrict__ pi,
    const float* __restrict__ phib, float* __restrict__ eq) {
  __shared__ float Qw[80][64];                   // 20 KB
  __shared__ __align__(16) float ps[4][16][64];  // 16 KB
  const int b = blockIdx.x;
  const int t0 = blockIdx.y * 16;
  const int half = blockIdx.z;
  const int tid = threadIdx.x;
  for (int i = tid; i < 80 * 64; i += 256) {
    int r = i >> 6, cc = i & 63;
    int tau = t0 - 63 + r;
    Qw[r][cc] = (tau >= 0) ? Q[(b * QROWS + tau) * NC + half * 64 + cc] : 0.f;
  }
  for (int i = tid; i < 1024; i += 256) {  // 1024 float4 = 4 scales x 256
    int s = i >> 8, rem = i & 255;
    ((float4*)ps)[i] = ((const float4*)(pi + ((long)s * NT + t0) * NLM))[rem];
  }
  __syncthreads();
  const int c = tid & 63, tg = tid >> 6;  // tg wave-uniform
  const float pb2 = phib[half * 64 + c] * TWO_LOG2E;
  for (int tt = tg; tt < 16; tt += 4) {
    const int ti = t0 + tt;
    const float Qt = Qw[tt + 64][c];
    float a0 = 0.f, a1 = 0.f, a2 = 0.f, a3 = 0.f;
#pragma unroll
    for (int l = 0; l < 64; l += 4) {
      float v[4];
#pragma unroll
      for (int u = 0; u < 4; ++u) {
        const float cl = TWO_LOG2E / (float)(l + u + 9);  // folded constant
        float y = (Qt - Qw[tt + 63 - (l + u)][c]) * cl + pb2;
        v[u] = rcp_fast(__builtin_exp2f(y) + 1.f);
      }
      float4 w0 = *(const float4*)&ps[0][tt][l];
      float4 w1 = *(const float4*)&ps[1][tt][l];
      float4 w2 = *(const float4*)&ps[2][tt][l];
      float4 w3 = *(const float4*)&ps[3][tt][l];
      a0 = fmaf(w0.x, v[0], a0); a0 = fmaf(w0.y, v[1], a0);
      a0 = fmaf(w0.z, v[2], a0); a0 = fmaf(w0.w, v[3], a0);
      a1 = fmaf(w1.x, v[0], a1); a1 = fmaf(w1.y, v[1], a1);
      a1 = fmaf(w1.z, v[2], a1); a1 = fmaf(w1.w, v[3], a1);
      a2 = fmaf(w2.x, v[0], a2); a2 = fmaf(w2.y, v[1], a2);
      a2 = fmaf(w2.z, v[2], a2); a2 = fmaf(w2.w, v[3], a2);
      a3 = fmaf(w3.x, v[0], a3); a3 = fmaf(w3.y, v[1], a3);
      a3 = fmaf(w3.z, v[2], a3); a3 = fmaf(w3.w, v[3], a3);
    }
    const long base = half * 64 + c;
    eq[((long)(0 * 8 + b) * NT + ti) * NC + base] = fmaf(-2.f, a0, 1.f);
    eq[((long)(1 * 8 + b) * NT + ti) * NC + base] = fmaf(-2.f, a1, 1.f);
    eq[((long)(2 * 8 + b) * NT + ti) * NC + base] = fmaf(-2.f, a2, 1.f);
    eq[((long)(3 * 8 + b) * NT + ti) * NC + base] = fmaf(-2.f, a3, 1.f);
  }
}

// K5a-data: qlocal = R @ e per (s,b,chunk) — tiled GEMM, 8t x 8c per lane.
__global__ __launch_bounds__(128) void k5a_data(const float* __restrict__ rt,
                                                float* __restrict__ eq) {
  __shared__ __align__(16) float rts[4096];    // [tp][t] 16 KB
  __shared__ __align__(16) float es[64][128];  // 32 KB
  const int sb = blockIdx.x;  // s*8+b
  const int s = sb >> 3;
  const int ch = blockIdx.y;
  const int tid = threadIdx.x;
  const float4* rsrc = (const float4*)(rt + ((long)s * NCH + ch) * 4096);
#pragma unroll
  for (int i = 0; i < 8; ++i) ((float4*)rts)[tid + 128 * i] = rsrc[tid + 128 * i];
  float* qb = eq + ((long)sb * NT + ch * 64) * NC;
  const float4* esrc = (const float4*)qb;
#pragma unroll
  for (int i = 0; i < 16; ++i) ((float4*)es)[tid + 128 * i] = esrc[tid + 128 * i];
  __syncthreads();
  const int t0 = (tid >> 4) * 8;  // 8 t-tiles
  const int c0 = (tid & 15) * 8;  // 16 c-tiles
  float acc[8][8];
#pragma unroll
  for (int i = 0; i < 8; ++i)
#pragma unroll
    for (int k = 0; k < 8; ++k) acc[i][k] = 0.f;
  for (int tp = 0; tp < 64; ++tp) {
    if (tp <= t0 + 7) {  // R is lower-triangular
      float4 r0 = *(const float4*)&rts[tp * 64 + t0];
      float4 r1 = *(const float4*)&rts[tp * 64 + t0 + 4];
      float4 e0 = *(const float4*)&es[tp][c0];
      float4 e1 = *(const float4*)&es[tp][c0 + 4];
      float rr[8] = {r0.x, r0.y, r0.z, r0.w, r1.x, r1.y, r1.z, r1.w};
      float ee[8] = {e0.x, e0.y, e0.z, e0.w, e1.x, e1.y, e1.z, e1.w};
#pragma unroll
      for (int i = 0; i < 8; ++i)
#pragma unroll
        for (int k = 0; k < 8; ++k) acc[i][k] = fmaf(rr[i], ee[k], acc[i][k]);
    }
  }
#pragma unroll
  for (int i = 0; i < 8; ++i) {
    float4* dst = (float4*)(qb + (t0 + i) * NC + c0);
    dst[0] = make_float4(acc[i][0], acc[i][1], acc[i][2], acc[i][3]);
    dst[1] = make_float4(acc[i][4], acc[i][5], acc[i][6], acc[i][7]);
  }
}

// K5b: cross-chunk combine, no LDS: history in the wave's own registers,
// fetched via v_readlane (compile-time lanes). 4-channel slices (R6 was 8):
// halves the serial per-chunk VALU path and doubles occupancy. Coef rows AND
// qlocal/klocal are double-buffered/prefetched one chunk ahead so no
// dependent global load sits on the serial path.
// Blocks 0..1023: q (sb x 32 slices of 4 channels); 1024..1027: k.
__global__ __launch_bounds__(64) void k5b_scan(const float* __restrict__ ctT,
                                               const float* __restrict__ klocal,
                                               float* __restrict__ eq,
                                               float* __restrict__ kout) {
  const int t = threadIdx.x;
  if (blockIdx.x < 1024) {
    const int sb = blockIdx.x >> 5, sl = blockIdx.x & 31;
    const int s = sb >> 3;
    const int c0 = sl * 4;
    const float* ctTs = ctT + (long)s * NCH * 4096 + t * 64;
    float* eqb = eq + (long)sb * NT * NC + c0;
    float4 crA[16], crB[16];
    {
      const float4* p = (const float4*)ctTs;
#pragma unroll
      for (int i = 0; i < 16; ++i) crA[i] = p[i];
    }
    float4 qlA = *(const float4*)(eqb + t * NC);
    float4 qlB;
    float hv[4];
#pragma unroll
    for (int i = 0; i < 4; ++i) hv[i] = 0.f;

#define K5B_BODY(CH, CR, QL)                                                 \
    {                                                                        \
      float acc[4];                                                          \
      _Pragma("unroll") for (int i = 0; i < 4; ++i) acc[i] = 0.f;            \
      const float* cr = (const float*)(CR);                                  \
      _Pragma("unroll") for (int j = 0; j < 64; ++j) {                       \
        float cv = cr[j];                                                    \
        _Pragma("unroll") for (int i = 0; i < 4; ++i)                        \
            acc[i] = fmaf(cv, readlane_f(hv[i], 63 - j), acc[i]);            \
      }                                                                      \
      hv[0] = acc[0] + (QL).x; hv[1] = acc[1] + (QL).y;                      \
      hv[2] = acc[2] + (QL).z; hv[3] = acc[3] + (QL).w;                      \
      *(float4*)(eqb + ((CH) * 64 + t) * NC) =                               \
          make_float4(hv[0], hv[1], hv[2], hv[3]);                           \
    }

#pragma unroll 1
    for (int ch = 0; ch < NCH; ch += 2) {
      {
        const float4* p = (const float4*)(ctTs + (ch + 1) * 4096);
#pragma unroll
        for (int i = 0; i < 16; ++i) crB[i] = p[i];
        qlB = *(const float4*)(eqb + ((ch + 1) * 64 + t) * NC);
      }
      K5B_BODY(ch, crA, qlA)
      if (ch + 2 < NCH) {
        const float4* p = (const float4*)(ctTs + (ch + 2) * 4096);
#pragma unroll
        for (int i = 0; i < 16; ++i) crA[i] = p[i];
        qlA = *(const float4*)(eqb + ((ch + 2) * 64 + t) * NC);
      }
      K5B_BODY(ch + 1, crB, qlB)
    }
#undef K5B_BODY
  } else {
    const int s = blockIdx.x - 1024;
    const float* ctTs = ctT + (long)s * NCH * 4096 + t * 64;
    const float* klb = klocal + (long)s * NCH * 64 + t;
    float4 crA[16], crB[16];
    {
      const float4* p = (const float4*)ctTs;
#pragma unroll
      for (int i = 0; i < 16; ++i) crA[i] = p[i];
    }
    float klA = klb[0], klB;
    float hk = 0.f;

#define K5BK_BODY(CH, CR, KL)                                                \
    {                                                                        \
      float acc = (KL);                                                      \
      const float* cr = (const float*)(CR);                                  \
      _Pragma("unroll") for (int j = 0; j < 64; ++j)                         \
          acc = fmaf(cr[j], readlane_f(hk, 63 - j), acc);                    \
      kout[s * NT + (CH) * 64 + t] = acc;                                    \
      hk = acc;                                                              \
    }

#pragma unroll 1
    for (int ch = 0; ch < NCH; ch += 2) {
      {
        const float4* p = (const float4*)(ctTs + (ch + 1) * 4096);
#pragma unroll
        for (int i = 0; i < 16; ++i) crB[i] = p[i];
        klB = klb[(ch + 1) * 64];
      }
      K5BK_BODY(ch, crA, klA)
      if (ch + 2 < NCH) {
        const float4* p = (const float4*)(ctTs + (ch + 2) * 4096);
#pragma unroll
        for (int i = 0; i < 16; ++i) crA[i] = p[i];
        klA = klb[(ch + 2) * 64];
      }
      K5BK_BODY(ch + 1, crB, klB)
    }
#undef K5BK_BODY
  }
}

// K6: rep = (q + 16*anchor)/(k+16) * (k/(k+16)); out = rep_flat @ mix_w + mix_b
// 16-row blocks (256 thr): halves redundant mixw L2 traffic vs 8-row.
__global__ __launch_bounds__(256) void k6_mix(
    const float* __restrict__ q, const float* __restrict__ kout,
    const float* __restrict__ anchor, const float* __restrict__ mixw,
    const float* __restrict__ mixb, float* __restrict__ out) {
  __shared__ __align__(16) float rsdata[16][512];  // 32 KB
  const int b = blockIdx.x;
  const int t0 = blockIdx.y * 16;
  const int tid = threadIdx.x;
  for (int i = tid; i < 16 * 512; i += 256) {
    int r = i >> 9, sc = i & 511;
    int s = sc >> 7, c = sc & 127;
    int ti = t0 + r;
    float qv = q[((long)(s * 8 + b) * NT + ti) * NC + c];
    float kv = kout[s * NT + ti];
    float d1 = rcp_fast(kv + 16.f);
    rsdata[r][sc] = (qv + 16.f * anchor[sc]) * d1 * (kv * d1);
  }
  __syncthreads();
  const int co = tid & 127, hf = tid >> 7;
  const int r0 = hf * 8;
  float mb = mixb[co];
  float acc[8];
#pragma unroll
  for (int r = 0; r < 8; ++r) acc[r] = mb;
  for (int kk = 0; kk < 512; kk += 4) {
    float wa = mixw[(kk + 0) * 128 + co];
    float wb = mixw[(kk + 1) * 128 + co];
    float wc = mixw[(kk + 2) * 128 + co];
    float wd = mixw[(kk + 3) * 128 + co];
#pragma unroll
    for (int r = 0; r < 8; ++r) {
      float4 rv = *(const float4*)&rsdata[r0 + r][kk];
      acc[r] = fmaf(rv.x, wa, acc[r]);
      acc[r] = fmaf(rv.y, wb, acc[r]);
      acc[r] = fmaf(rv.z, wc, acc[r]);
      acc[r] = fmaf(rv.w, wd, acc[r]);
    }
  }
#pragma unroll
  for (int r = 0; r < 8; ++r)
    out[((long)b * NT + t0 + r0 + r) * NC + co] = acc[r];
}

extern "C" void kernel_launch(void* const* d_in, const int* in_sizes, int n_in,
                              void* d_out, int out_size, void* d_ws, size_t ws_size,
                              hipStream_t stream) {
  const float* x = (const float*)d_in[0];
  const float* W = (const float*)d_in[1];
  const float* bias = (const float*)d_in[2];
  const float* phiw = (const float*)d_in[3];
  const float* phib = (const float*)d_in[4];
  const float* anchor = (const float*)d_in[5];
  const float* logw = (const float*)d_in[6];
  const float* mixw = (const float*)d_in[7];
  const float* mixb = (const float*)d_in[8];
  float* out = (float*)d_out;

  float* ws = (float*)d_ws;
  float* Q = ws;                                     // 8*2049*128 = 2,098,176
  float* pi = Q + (long)NB * QROWS * NC;             // 4*2048*64  =   524,288
  float* eq = pi + (long)NS * NT * NLM;              // 32*2048*128= 8,388,608
  float* coefTT = eq + (long)NS * NB * NT * NC;      //               524,288
  float* rtb = coefTT + (long)NS * NCH * 4096;       //               524,288
  float* klocal = rtb + (long)NS * NCH * 4096;       //                 8,192
  float* kout = klocal + (long)NS * NCH * 64;        //                 8,192
  float* logZt = kout + (long)NS * NT;               //                 8,196
  float* S2 = logZt + (long)NS * QROWS;              //                32,768

  hipLaunchKernelGGL(k1_uv, dim3(NB * NT / 8), dim3(128), 0, stream, x, W, bias, phiw, Q);
  hipLaunchKernelGGL(k2a_sums, dim3(NB, NCH), dim3(128), 0, stream, Q, S2);
  hipLaunchKernelGGL(k2c_fix, dim3(NB, NCH), dim3(128), 0, stream, Q, S2);
  hipLaunchKernelGGL(k3ab_logz, dim3(NS), dim3(64), 0, stream, logw, logZt);
  hipLaunchKernelGGL(k5a_basis, dim3(NS, NCH), dim3(128), 0, stream, logw, logZt, pi, rtb, coefTT, klocal);
  hipLaunchKernelGGL(k4_e, dim3(NB, NT / 16, 2), dim3(256), 0, stream, Q, pi, phib, eq);
  hipLaunchKernelGGL(k5a_data, dim3(NS * NB, NCH), dim3(128), 0, stream, rtb, eq);
  hipLaunchKernelGGL(k5b_scan, dim3(1028), dim3(64), 0, stream, coefTT, klocal, eq, kout);
  hipLaunchKernelGGL(k6_mix, dim3(NB, NT / 16), dim3(256), 0, stream, eq, kout, anchor, mixw, mixb, out);
}

// Round 9
// 498.430 us; speedup vs baseline: 1.0076x; 1.0076x over previous
//
#include <hip/hip_runtime.h>
#include <math.h>

// Problem constants
#define NB 8
#define NT 2048
#define NC 128
#define NLM 64
#define NS 4
#define QROWS 2049
#define NCH 32  // 2048 / 64 chunks

#define TWO_LOG2E 2.885390081777927f

typedef float fv4 __attribute__((ext_vector_type(4)));  // clang vector: OK for nontemporal builtins

__device__ __forceinline__ float rcp_fast(float x) {
  return __builtin_amdgcn_rcpf(x);
}

__device__ __forceinline__ float readlane_f(float v, int lane) {
  return __int_as_float(__builtin_amdgcn_readlane(__float_as_int(v), lane));
}

// ---------------------------------------------------------------------------
// Tiled 64-step local linear scan (forward substitution); all indices
// compile-time so q[4][16] stays in VGPRs.
// ---------------------------------------------------------------------------
template <typename PF, typename DF>
__device__ __forceinline__ void tri_scan64(PF P, DF D, float q[4][16]) {
#pragma unroll
  for (int tau = 0; tau < 4; ++tau) {
    float acc[16];
#pragma unroll
    for (int i = 0; i < 16; ++i) acc[i] = D(tau * 16 + i);
#pragma unroll
    for (int p = 0; p < 4; ++p) {
      if (p < tau) {
#pragma unroll
        for (int i = 0; i < 16; ++i) {
          const int t = tau * 16 + i;
#pragma unroll
          for (int i2 = 0; i2 < 16; ++i2) {
            acc[i] = fmaf(P(t, t - (p * 16 + i2) - 1), q[p][i2], acc[i]);
          }
        }
      }
    }
#pragma unroll
    for (int i = 0; i < 16; ++i) {
      const int t = tau * 16 + i;
#pragma unroll
      for (int i2 = 0; i2 < 16; ++i2) {
        if (i2 < i) acc[i] = fmaf(P(t, i - i2 - 1), q[tau][i2], acc[i]);
      }
      q[tau][i] = acc[i];
    }
  }
}

// K1: per 16 rows (b,t): z = x@W + b ; u = [cos,sin]/sqrt(dh) ; V = u @ phi_w
// 16 rows/block halves weight (W,phiw) L2 re-fetch vs 8-row version.
__global__ __launch_bounds__(128) void k1_uv(
    const float* __restrict__ x, const float* __restrict__ W,
    const float* __restrict__ bias, const float* __restrict__ phiw,
    float* __restrict__ Q) {
  __shared__ __align__(16) float xs[16][128];  // 8 KB
  __shared__ float us[16][256];                // 16 KB
  const int j = threadIdx.x;
  const int bt0 = blockIdx.x * 16;
  {
    const float4* x4 = (const float4*)(x + (long)bt0 * NC);
#pragma unroll
    for (int i = 0; i < 4; ++i)
      ((float4*)xs)[j + 128 * i] = x4[j + 128 * i];
  }
  __syncthreads();
  float z[16];
  const float bj = bias[j];
#pragma unroll
  for (int r = 0; r < 16; ++r) z[r] = bj;
  for (int k = 0; k < 128; ++k) {
    float w = W[k * 128 + j];
#pragma unroll
    for (int r = 0; r < 16; ++r) z[r] = fmaf(xs[r][k], w, z[r]);
  }
  const float rs = 0.08838834764831845f;  // 1/sqrt(128)
#pragma unroll
  for (int r = 0; r < 16; ++r) {
    float sv, cv;
    sincosf(z[r], &sv, &cv);
    us[r][j] = cv * rs;
    us[r][128 + j] = sv * rs;
  }
  __syncthreads();
  float a[16];
#pragma unroll
  for (int r = 0; r < 16; ++r) a[r] = 0.f;
  for (int k = 0; k < 256; ++k) {
    float w = phiw[k * 128 + j];
#pragma unroll
    for (int r = 0; r < 16; ++r) a[r] = fmaf(us[r][k], w, a[r]);
  }
#pragma unroll
  for (int r = 0; r < 16; ++r) {
    int bt = bt0 + r;
    int b = bt >> 11, t = bt & 2047;
    Q[(b * QROWS + t + 1) * NC + j] = a[r];
  }
}

// K2a: per-chunk raw sums, float4 channels, 16-row groups + LDS reduce.
__global__ __launch_bounds__(128) void k2a_sums(const float* __restrict__ Q,
                                                float* __restrict__ S2) {
  __shared__ float4 part[4][32];
  const int b = blockIdx.x, ch = blockIdx.y;
  const int g = threadIdx.x >> 5, c4 = threadIdx.x & 31;
  const float4* Q4 = (const float4*)(Q + (long)(b * QROWS + ch * 64 + 1) * NC);
  float4 acc = make_float4(0.f, 0.f, 0.f, 0.f);
#pragma unroll
  for (int i = 0; i < 16; ++i) {
    float4 v = Q4[(g * 16 + i) * 32 + c4];
    acc.x += v.x; acc.y += v.y; acc.z += v.z; acc.w += v.w;
  }
  part[g][c4] = acc;
  __syncthreads();
  if (g == 0) {
    float4 p0 = part[0][c4], p1 = part[1][c4], p2 = part[2][c4], p3 = part[3][c4];
    ((float4*)(S2 + (long)(b * NCH + ch) * NC))[c4] =
        make_float4(p0.x + p1.x + p2.x + p3.x, p0.y + p1.y + p2.y + p3.y,
                    p0.z + p1.z + p2.z + p3.z, p0.w + p1.w + p2.w + p3.w);
  }
}

// K2c: block (b,ch) sums exclusive prefix of chunk sums + own group prefix,
// then fixes up its 16-row group (serial depth 16, float4).
__global__ __launch_bounds__(128) void k2c_fix(float* __restrict__ Q,
                                               const float* __restrict__ S2) {
  __shared__ float4 gsum[4][32];
  const int b = blockIdx.x, ch = blockIdx.y;
  const int g = threadIdx.x >> 5, c4 = threadIdx.x & 31;
  if (ch == 0 && g == 0)
    ((float4*)(Q + (long)(b * QROWS) * NC))[c4] = make_float4(0.f, 0.f, 0.f, 0.f);
  float4 run = make_float4(0.f, 0.f, 0.f, 0.f);
  for (int i = 0; i < ch; ++i) {
    float4 v = ((const float4*)(S2 + (long)(b * NCH + i) * NC))[c4];
    run.x += v.x; run.y += v.y; run.z += v.z; run.w += v.w;
  }
  float4* Q4 = (float4*)(Q + (long)(b * QROWS + ch * 64 + 1) * NC);
  {
    float4 gs = make_float4(0.f, 0.f, 0.f, 0.f);
#pragma unroll
    for (int i = 0; i < 16; ++i) {
      float4 v = Q4[(g * 16 + i) * 32 + c4];
      gs.x += v.x; gs.y += v.y; gs.z += v.z; gs.w += v.w;
    }
    gsum[g][c4] = gs;
  }
  __syncthreads();
  for (int gp = 0; gp < 3; ++gp) {
    if (gp < g) {
      float4 v = gsum[gp][c4];
      run.x += v.x; run.y += v.y; run.z += v.z; run.w += v.w;
    }
  }
#pragma unroll 4
  for (int i = 0; i < 16; ++i) {
    float4* p = Q4 + (g * 16 + i) * 32 + c4;
    float4 v = *p;
    run.x += v.x; run.y += v.y; run.z += v.z; run.w += v.w;
    *p = run;
  }
}

// K3ab fused: unit-response matrix mT of the Z recurrence (LDS) + 32
// sequential chunk-steps of the rescaled linear logZ evolution. Per s.
__global__ __launch_bounds__(64) void k3ab_logz(const float* __restrict__ logw,
                                                float* __restrict__ logZt) {
  const int s = blockIdx.x;
  const int j = threadIdx.x;  // doubles as t in phase 2
  __shared__ float wx[64];
  __shared__ float mTs[64][65];  // [j][t], padded (writes are row-per-lane)
  __shared__ float Zr[64];
  wx[j] = __expf(logw[s * NLM + j]);
  __syncthreads();
  float q[4][16];
  tri_scan64([&](int t, int l) { return wx[l]; },
             [&](int t) { int l = t + j; return (l < 64) ? wx[l] : 0.f; }, q);
#pragma unroll
  for (int tau = 0; tau < 4; ++tau)
#pragma unroll
    for (int i = 0; i < 16; ++i) mTs[j][tau * 16 + i] = q[tau][i];
  // phase 2
  const int t = j;
  Zr[t] = (t == 0) ? 1.f : 0.f;
  if (t == 0) logZt[s * QROWS] = 0.f;
  float off = 0.f;
  __syncthreads();
  for (int ch = 0; ch < NCH; ++ch) {
    float acc = 0.f;
#pragma unroll 8
    for (int jj = 0; jj < 64; ++jj) acc = fmaf(mTs[jj][t], Zr[jj], acc);
    logZt[s * QROWS + ch * 64 + 1 + t] = logf(acc) + off;
    float mx = acc;
#pragma unroll
    for (int o = 32; o; o >>= 1) mx = fmaxf(mx, __shfl_xor(mx, o));
    __syncthreads();
    Zr[63 - t] = acc / mx;
    off += logf(mx);
    __syncthreads();
  }
}

// K5a-basis (per s,ch), also computes pi for its chunk in-LDS (k3c fused):
// phase 0: pi[tt][l] = softmax_l(lw[l] + logZ[ti-l]); -> LDS psd + global pi.
// phase 1: threads 0..63: impulse-response columns R (rt, [tp][t]);
//          threads 64..127: history responses ctT ([t][j]); klocal = rowsum R.
__global__ __launch_bounds__(128) void k5a_basis(const float* __restrict__ logw,
                                                 const float* __restrict__ logZt,
                                                 float* __restrict__ pig,
                                                 float* __restrict__ rt,
                                                 float* __restrict__ ctT,
                                                 float* __restrict__ klocal) {
  __shared__ __align__(16) float psd[4096];
  __shared__ float Rl[64][65];
  __shared__ float lzs[128];
  __shared__ float lws[64];
  const int s = blockIdx.x, ch = blockIdx.y;
  const int tid = threadIdx.x;
  {
    int idx = ch * 64 - 63 + tid;
    lzs[tid] = (idx >= 0) ? logZt[s * QROWS + idx] : -INFINITY;
    if (tid < 64) lws[tid] = logw[s * NLM + tid];
  }
  __syncthreads();
  {
    const int l = tid & 63, wv = tid >> 6;
    for (int tt = wv; tt < 64; tt += 2) {
      float la = lws[l] + lzs[tt + 63 - l];
      float m = la;
#pragma unroll
      for (int o = 32; o; o >>= 1) m = fmaxf(m, __shfl_xor(m, o));
      float p = __expf(la - m);
      float zs = p;
#pragma unroll
      for (int o = 32; o; o >>= 1) zs += __shfl_xor(zs, o);
      float pv = p * rcp_fast(zs);
      psd[tt * 64 + l] = pv;
      pig[((long)s * NT + ch * 64 + tt) * NLM + l] = pv;
    }
  }
  __syncthreads();
  float q[4][16];
  if (tid < 64) {
    const int tp = tid;  // impulse position
    tri_scan64([&](int t, int l) { return psd[t * 64 + l]; },
               [&](int t) { return (t == tp) ? 1.f : 0.f; }, q);
    float* rrow = rt + (((long)s * NCH + ch) * 64 + tp) * 64;  // [tp][t]
#pragma unroll
    for (int tau = 0; tau < 4; ++tau)
#pragma unroll
      for (int i = 0; i < 16; ++i) {
        rrow[tau * 16 + i] = q[tau][i];
        Rl[tp][tau * 16 + i] = q[tau][i];
      }
  } else {
    const int j = tid - 64;  // history lookback j+1
    tri_scan64([&](int t, int l) { return psd[t * 64 + l]; },
               [&](int t) { int l = t + j; return (l < 64) ? psd[t * 64 + l] : 0.f; }, q);
    float* ctb = ctT + ((long)s * NCH + ch) * 4096;  // [t][j]
#pragma unroll
    for (int tau = 0; tau < 4; ++tau)
#pragma unroll
      for (int i = 0; i < 16; ++i) ctb[(tau * 16 + i) * 64 + j] = q[tau][i];
  }
  __syncthreads();
  if (tid < 64) {  // klocal[t] = sum_t' R[t][t']
    float acc = 0.f;
#pragma unroll 8
    for (int tp = 0; tp < 64; ++tp) acc += Rl[tp][tid];
    klocal[((long)s * NCH + ch) * 64 + tid] = acc;
  }
}

// K4: e[s,b,ti,c] = 1 - 2 * sum_l pi[s,ti,l] * rcp(exp2(y)+1)
__global__ __launch_bounds__(256) void k4_e(
    const float* __restrict__ Q, const float* __restrict__ pi,
    const float* __restrict__ phib, float* __restrict__ eq) {
  __shared__ float Qw[80][64];                   // 20 KB
  __shared__ __align__(16) float ps[4][16][64];  // 16 KB
  const int b = blockIdx.x;
  const int t0 = blockIdx.y * 16;
  const int half = blockIdx.z;
  const int tid = threadIdx.x;
  for (int i = tid; i < 80 * 64; i += 256) {
    int r = i >> 6, cc = i & 63;
    int tau = t0 - 63 + r;
    Qw[r][cc] = (tau >= 0) ? Q[(b * QROWS + tau) * NC + half * 64 + cc] : 0.f;
  }
  for (int i = tid; i < 1024; i += 256) {  // 1024 float4 = 4 scales x 256
    int s = i >> 8, rem = i & 255;
    ((float4*)ps)[i] = ((const float4*)(pi + ((long)s * NT + t0) * NLM))[rem];
  }
  __syncthreads();
  const int c = tid & 63, tg = tid >> 6;  // tg wave-uniform
  const float pb2 = phib[half * 64 + c] * TWO_LOG2E;
  for (int tt = tg; tt < 16; tt += 4) {
    const int ti = t0 + tt;
    const float Qt = Qw[tt + 64][c];
    float a0 = 0.f, a1 = 0.f, a2 = 0.f, a3 = 0.f;
#pragma unroll
    for (int l = 0; l < 64; l += 4) {
      float v[4];
#pragma unroll
      for (int u = 0; u < 4; ++u) {
        const float cl = TWO_LOG2E / (float)(l + u + 9);  // folded constant
        float y = (Qt - Qw[tt + 63 - (l + u)][c]) * cl + pb2;
        v[u] = rcp_fast(__builtin_exp2f(y) + 1.f);
      }
      float4 w0 = *(const float4*)&ps[0][tt][l];
      float4 w1 = *(const float4*)&ps[1][tt][l];
      float4 w2 = *(const float4*)&ps[2][tt][l];
      float4 w3 = *(const float4*)&ps[3][tt][l];
      a0 = fmaf(w0.x, v[0], a0); a0 = fmaf(w0.y, v[1], a0);
      a0 = fmaf(w0.z, v[2], a0); a0 = fmaf(w0.w, v[3], a0);
      a1 = fmaf(w1.x, v[0], a1); a1 = fmaf(w1.y, v[1], a1);
      a1 = fmaf(w1.z, v[2], a1); a1 = fmaf(w1.w, v[3], a1);
      a2 = fmaf(w2.x, v[0], a2); a2 = fmaf(w2.y, v[1], a2);
      a2 = fmaf(w2.z, v[2], a2); a2 = fmaf(w2.w, v[3], a2);
      a3 = fmaf(w3.x, v[0], a3); a3 = fmaf(w3.y, v[1], a3);
      a3 = fmaf(w3.z, v[2], a3); a3 = fmaf(w3.w, v[3], a3);
    }
    const long base = half * 64 + c;
    eq[((long)(0 * 8 + b) * NT + ti) * NC + base] = fmaf(-2.f, a0, 1.f);
    eq[((long)(1 * 8 + b) * NT + ti) * NC + base] = fmaf(-2.f, a1, 1.f);
    eq[((long)(2 * 8 + b) * NT + ti) * NC + base] = fmaf(-2.f, a2, 1.f);
    eq[((long)(3 * 8 + b) * NT + ti) * NC + base] = fmaf(-2.f, a3, 1.f);
  }
}

// K5a-data: qlocal = R @ e per (s,b,chunk) — tiled GEMM, 8t x 8c per lane.
__global__ __launch_bounds__(128) void k5a_data(const float* __restrict__ rt,
                                                float* __restrict__ eq) {
  __shared__ __align__(16) float rts[4096];    // [tp][t] 16 KB
  __shared__ __align__(16) float es[64][128];  // 32 KB
  const int sb = blockIdx.x;  // s*8+b
  const int s = sb >> 3;
  const int ch = blockIdx.y;
  const int tid = threadIdx.x;
  const float4* rsrc = (const float4*)(rt + ((long)s * NCH + ch) * 4096);
#pragma unroll
  for (int i = 0; i < 8; ++i) ((float4*)rts)[tid + 128 * i] = rsrc[tid + 128 * i];
  float* qb = eq + ((long)sb * NT + ch * 64) * NC;
  const float4* esrc = (const float4*)qb;
#pragma unroll
  for (int i = 0; i < 16; ++i) ((float4*)es)[tid + 128 * i] = esrc[tid + 128 * i];
  __syncthreads();
  const int t0 = (tid >> 4) * 8;  // 8 t-tiles
  const int c0 = (tid & 15) * 8;  // 16 c-tiles
  float acc[8][8];
#pragma unroll
  for (int i = 0; i < 8; ++i)
#pragma unroll
    for (int k = 0; k < 8; ++k) acc[i][k] = 0.f;
  for (int tp = 0; tp < 64; ++tp) {
    if (tp <= t0 + 7) {  // R is lower-triangular
      float4 r0 = *(const float4*)&rts[tp * 64 + t0];
      float4 r1 = *(const float4*)&rts[tp * 64 + t0 + 4];
      float4 e0 = *(const float4*)&es[tp][c0];
      float4 e1 = *(const float4*)&es[tp][c0 + 4];
      float rr[8] = {r0.x, r0.y, r0.z, r0.w, r1.x, r1.y, r1.z, r1.w};
      float ee[8] = {e0.x, e0.y, e0.z, e0.w, e1.x, e1.y, e1.z, e1.w};
#pragma unroll
      for (int i = 0; i < 8; ++i)
#pragma unroll
        for (int k = 0; k < 8; ++k) acc[i][k] = fmaf(rr[i], ee[k], acc[i][k]);
    }
  }
#pragma unroll
  for (int i = 0; i < 8; ++i) {
    float4* dst = (float4*)(qb + (t0 + i) * NC + c0);
    dst[0] = make_float4(acc[i][0], acc[i][1], acc[i][2], acc[i][3]);
    dst[1] = make_float4(acc[i][4], acc[i][5], acc[i][6], acc[i][7]);
  }
}

// K5b: cross-chunk combine, no LDS: history in the wave's own registers via
// v_readlane (compile-time lanes). 8-channel slices (512 q-blocks — the R7
// 4-ch split doubled ctT fetch redundancy and regressed). Coef rows AND
// qlocal/klocal double-buffered/prefetched one chunk ahead. Nontemporal
// eq accesses (fv4 clang-vector type) keep the 2 MB ctT set resident in L2.
// Blocks 0..511: q (sb x 16 slices of 8 channels); 512..515: k.
__global__ __launch_bounds__(64, 1) void k5b_scan(const float* __restrict__ ctT,
                                                  const float* __restrict__ klocal,
                                                  float* __restrict__ eq,
                                                  float* __restrict__ kout) {
  const int t = threadIdx.x;
  if (blockIdx.x < 512) {
    const int sb = blockIdx.x >> 4, sl = blockIdx.x & 15;
    const int s = sb >> 3;
    const int c0 = sl * 8;
    const float* ctTs = ctT + (long)s * NCH * 4096 + t * 64;
    float* eqb = eq + (long)sb * NT * NC + c0;
    float4 crA[16], crB[16];
    {
      const float4* p = (const float4*)ctTs;
#pragma unroll
      for (int i = 0; i < 16; ++i) crA[i] = p[i];
    }
    fv4 qlA0 = __builtin_nontemporal_load((const fv4*)(eqb + t * NC));
    fv4 qlA1 = __builtin_nontemporal_load((const fv4*)(eqb + t * NC) + 1);
    fv4 qlB0, qlB1;
    float hv[8];
#pragma unroll
    for (int i = 0; i < 8; ++i) hv[i] = 0.f;

#define K5B_BODY(CH, CR, QL0, QL1)                                           \
    {                                                                        \
      float acc[8];                                                          \
      _Pragma("unroll") for (int i = 0; i < 8; ++i) acc[i] = 0.f;            \
      const float* cr = (const float*)(CR);                                  \
      _Pragma("unroll") for (int j = 0; j < 64; ++j) {                       \
        float cv = cr[j];                                                    \
        _Pragma("unroll") for (int i = 0; i < 8; ++i)                        \
            acc[i] = fmaf(cv, readlane_f(hv[i], 63 - j), acc[i]);            \
      }                                                                      \
      hv[0] = acc[0] + (QL0).x; hv[1] = acc[1] + (QL0).y;                    \
      hv[2] = acc[2] + (QL0).z; hv[3] = acc[3] + (QL0).w;                    \
      hv[4] = acc[4] + (QL1).x; hv[5] = acc[5] + (QL1).y;                    \
      hv[6] = acc[6] + (QL1).z; hv[7] = acc[7] + (QL1).w;                    \
      fv4* qp = (fv4*)(eqb + ((CH) * 64 + t) * NC);                          \
      fv4 s0 = {hv[0], hv[1], hv[2], hv[3]};                                 \
      fv4 s1 = {hv[4], hv[5], hv[6], hv[7]};                                 \
      __builtin_nontemporal_store(s0, qp);                                   \
      __builtin_nontemporal_store(s1, qp + 1);                               \
    }

#pragma unroll 1
    for (int ch = 0; ch < NCH; ch += 2) {
      {
        const float4* p = (const float4*)(ctTs + (ch + 1) * 4096);
#pragma unroll
        for (int i = 0; i < 16; ++i) crB[i] = p[i];
        const fv4* qn = (const fv4*)(eqb + ((ch + 1) * 64 + t) * NC);
        qlB0 = __builtin_nontemporal_load(qn);
        qlB1 = __builtin_nontemporal_load(qn + 1);
      }
      K5B_BODY(ch, crA, qlA0, qlA1)
      if (ch + 2 < NCH) {
        const float4* p = (const float4*)(ctTs + (ch + 2) * 4096);
#pragma unroll
        for (int i = 0; i < 16; ++i) crA[i] = p[i];
        const fv4* qn = (const fv4*)(eqb + ((ch + 2) * 64 + t) * NC);
        qlA0 = __builtin_nontemporal_load(qn);
        qlA1 = __builtin_nontemporal_load(qn + 1);
      }
      K5B_BODY(ch + 1, crB, qlB0, qlB1)
    }
#undef K5B_BODY
  } else {
    const int s = blockIdx.x - 512;
    const float* ctTs = ctT + (long)s * NCH * 4096 + t * 64;
    const float* klb = klocal + (long)s * NCH * 64 + t;
    float4 crA[16], crB[16];
    {
      const float4* p = (const float4*)ctTs;
#pragma unroll
      for (int i = 0; i < 16; ++i) crA[i] = p[i];
    }
    float klA = klb[0], klB;
    float hk = 0.f;

#define K5BK_BODY(CH, CR, KL)                                                \
    {                                                                        \
      float acc = (KL);                                                      \
      const float* cr = (const float*)(CR);                                  \
      _Pragma("unroll") for (int j = 0; j < 64; ++j)                         \
          acc = fmaf(cr[j], readlane_f(hk, 63 - j), acc);                    \
      kout[s * NT + (CH) * 64 + t] = acc;                                    \
      hk = acc;                                                              \
    }

#pragma unroll 1
    for (int ch = 0; ch < NCH; ch += 2) {
      {
        const float4* p = (const float4*)(ctTs + (ch + 1) * 4096);
#pragma unroll
        for (int i = 0; i < 16; ++i) crB[i] = p[i];
        klB = klb[(ch + 1) * 64];
      }
      K5BK_BODY(ch, crA, klA)
      if (ch + 2 < NCH) {
        const float4* p = (const float4*)(ctTs + (ch + 2) * 4096);
#pragma unroll
        for (int i = 0; i < 16; ++i) crA[i] = p[i];
        klA = klb[(ch + 2) * 64];
      }
      K5BK_BODY(ch + 1, crB, klB)
    }
#undef K5BK_BODY
  }
}

// K6: rep = (q + 16*anchor)/(k+16) * (k/(k+16)); out = rep_flat @ mix_w + mix_b
__global__ __launch_bounds__(256) void k6_mix(
    const float* __restrict__ q, const float* __restrict__ kout,
    const float* __restrict__ anchor, const float* __restrict__ mixw,
    const float* __restrict__ mixb, float* __restrict__ out) {
  __shared__ __align__(16) float rsdata[16][512];  // 32 KB
  const int b = blockIdx.x;
  const int t0 = blockIdx.y * 16;
  const int tid = threadIdx.x;
  for (int i = tid; i < 16 * 512; i += 256) {
    int r = i >> 9, sc = i & 511;
    int s = sc >> 7, c = sc & 127;
    int ti = t0 + r;
    float qv = q[((long)(s * 8 + b) * NT + ti) * NC + c];
    float kv = kout[s * NT + ti];
    float d1 = rcp_fast(kv + 16.f);
    rsdata[r][sc] = (qv + 16.f * anchor[sc]) * d1 * (kv * d1);
  }
  __syncthreads();
  const int co = tid & 127, hf = tid >> 7;
  const int r0 = hf * 8;
  float mb = mixb[co];
  float acc[8];
#pragma unroll
  for (int r = 0; r < 8; ++r) acc[r] = mb;
  for (int kk = 0; kk < 512; kk += 4) {
    float wa = mixw[(kk + 0) * 128 + co];
    float wb = mixw[(kk + 1) * 128 + co];
    float wc = mixw[(kk + 2) * 128 + co];
    float wd = mixw[(kk + 3) * 128 + co];
#pragma unroll
    for (int r = 0; r < 8; ++r) {
      float4 rv = *(const float4*)&rsdata[r0 + r][kk];
      acc[r] = fmaf(rv.x, wa, acc[r]);
      acc[r] = fmaf(rv.y, wb, acc[r]);
      acc[r] = fmaf(rv.z, wc, acc[r]);
      acc[r] = fmaf(rv.w, wd, acc[r]);
    }
  }
#pragma unroll
  for (int r = 0; r < 8; ++r)
    out[((long)b * NT + t0 + r0 + r) * NC + co] = acc[r];
}

extern "C" void kernel_launch(void* const* d_in, const int* in_sizes, int n_in,
                              void* d_out, int out_size, void* d_ws, size_t ws_size,
                              hipStream_t stream) {
  const float* x = (const float*)d_in[0];
  const float* W = (const float*)d_in[1];
  const float* bias = (const float*)d_in[2];
  const float* phiw = (const float*)d_in[3];
  const float* phib = (const float*)d_in[4];
  const float* anchor = (const float*)d_in[5];
  const float* logw = (const float*)d_in[6];
  const float* mixw = (const float*)d_in[7];
  const float* mixb = (const float*)d_in[8];
  float* out = (float*)d_out;

  float* ws = (float*)d_ws;
  float* Q = ws;                                     // 8*2049*128 = 2,098,176
  float* pi = Q + (long)NB * QROWS * NC;             // 4*2048*64  =   524,288
  float* eq = pi + (long)NS * NT * NLM;              // 32*2048*128= 8,388,608
  float* coefTT = eq + (long)NS * NB * NT * NC;      //               524,288
  float* rtb = coefTT + (long)NS * NCH * 4096;       //               524,288
  float* klocal = rtb + (long)NS * NCH * 4096;       //                 8,192
  float* kout = klocal + (long)NS * NCH * 64;        //                 8,192
  float* logZt = kout + (long)NS * NT;               //                 8,196
  float* S2 = logZt + (long)NS * QROWS;              //                32,768

  hipLaunchKernelGGL(k1_uv, dim3(NB * NT / 16), dim3(128), 0, stream, x, W, bias, phiw, Q);
  hipLaunchKernelGGL(k2a_sums, dim3(NB, NCH), dim3(128), 0, stream, Q, S2);
  hipLaunchKernelGGL(k2c_fix, dim3(NB, NCH), dim3(128), 0, stream, Q, S2);
  hipLaunchKernelGGL(k3ab_logz, dim3(NS), dim3(64), 0, stream, logw, logZt);
  hipLaunchKernelGGL(k5a_basis, dim3(NS, NCH), dim3(128), 0, stream, logw, logZt, pi, rtb, coefTT, klocal);
  hipLaunchKernelGGL(k4_e, dim3(NB, NT / 16, 2), dim3(256), 0, stream, Q, pi, phib, eq);
  hipLaunchKernelGGL(k5a_data, dim3(NS * NB, NCH), dim3(128), 0, stream, rtb, eq);
  hipLaunchKernelGGL(k5b_scan, dim3(516), dim3(64), 0, stream, coefTT, klocal, eq, kout);
  hipLaunchKernelGGL(k6_mix, dim3(NB, NT / 16), dim3(256), 0, stream, eq, kout, anchor, mixw, mixb, out);
}

// Round 10
// 454.372 us; speedup vs baseline: 1.1053x; 1.0970x over previous
//
#include <hip/hip_runtime.h>
#include <math.h>

// Problem constants
#define NB 8
#define NT 2048
#define NC 128
#define NLM 64
#define NS 4
#define QROWS 2049
#define NCH 32  // 2048 / 64 chunks

#define TWO_LOG2E 2.885390081777927f

__device__ __forceinline__ float rcp_fast(float x) {
  return __builtin_amdgcn_rcpf(x);
}

__device__ __forceinline__ float readlane_f(float v, int lane) {
  return __int_as_float(__builtin_amdgcn_readlane(__float_as_int(v), lane));
}

// ---------------------------------------------------------------------------
// Tiled 64-step local linear scan (forward substitution); all indices
// compile-time so q[4][16] stays in VGPRs.
// ---------------------------------------------------------------------------
template <typename PF, typename DF>
__device__ __forceinline__ void tri_scan64(PF P, DF D, float q[4][16]) {
#pragma unroll
  for (int tau = 0; tau < 4; ++tau) {
    float acc[16];
#pragma unroll
    for (int i = 0; i < 16; ++i) acc[i] = D(tau * 16 + i);
#pragma unroll
    for (int p = 0; p < 4; ++p) {
      if (p < tau) {
#pragma unroll
        for (int i = 0; i < 16; ++i) {
          const int t = tau * 16 + i;
#pragma unroll
          for (int i2 = 0; i2 < 16; ++i2) {
            acc[i] = fmaf(P(t, t - (p * 16 + i2) - 1), q[p][i2], acc[i]);
          }
        }
      }
    }
#pragma unroll
    for (int i = 0; i < 16; ++i) {
      const int t = tau * 16 + i;
#pragma unroll
      for (int i2 = 0; i2 < 16; ++i2) {
        if (i2 < i) acc[i] = fmaf(P(t, i - i2 - 1), q[tau][i2], acc[i]);
      }
      q[tau][i] = acc[i];
    }
  }
}

// K1: per 16 rows (b,t): z = x@W + b ; u = [cos,sin]/sqrt(dh) ; V = u @ phi_w
__global__ __launch_bounds__(128) void k1_uv(
    const float* __restrict__ x, const float* __restrict__ W,
    const float* __restrict__ bias, const float* __restrict__ phiw,
    float* __restrict__ Q) {
  __shared__ __align__(16) float xs[16][128];  // 8 KB
  __shared__ float us[16][256];                // 16 KB
  const int j = threadIdx.x;
  const int bt0 = blockIdx.x * 16;
  {
    const float4* x4 = (const float4*)(x + (long)bt0 * NC);
#pragma unroll
    for (int i = 0; i < 4; ++i)
      ((float4*)xs)[j + 128 * i] = x4[j + 128 * i];
  }
  __syncthreads();
  float z[16];
  const float bj = bias[j];
#pragma unroll
  for (int r = 0; r < 16; ++r) z[r] = bj;
  for (int k = 0; k < 128; ++k) {
    float w = W[k * 128 + j];
#pragma unroll
    for (int r = 0; r < 16; ++r) z[r] = fmaf(xs[r][k], w, z[r]);
  }
  const float rs = 0.08838834764831845f;  // 1/sqrt(128)
#pragma unroll
  for (int r = 0; r < 16; ++r) {
    float sv, cv;
    sincosf(z[r], &sv, &cv);
    us[r][j] = cv * rs;
    us[r][128 + j] = sv * rs;
  }
  __syncthreads();
  float a[16];
#pragma unroll
  for (int r = 0; r < 16; ++r) a[r] = 0.f;
  for (int k = 0; k < 256; ++k) {
    float w = phiw[k * 128 + j];
#pragma unroll
    for (int r = 0; r < 16; ++r) a[r] = fmaf(us[r][k], w, a[r]);
  }
#pragma unroll
  for (int r = 0; r < 16; ++r) {
    int bt = bt0 + r;
    int b = bt >> 11, t = bt & 2047;
    Q[(b * QROWS + t + 1) * NC + j] = a[r];
  }
}

// K23 merged: blocks 0..255 = k2a (per-chunk raw sums of V);
//             blocks 256..259 = k3ab (serial logZ chunk evolution, per s).
// Independent families — merging removes a launch gap and overlaps the
// 4-block serial scan under the 256-block streaming sum.
__global__ __launch_bounds__(128) void k23_sums_logz(
    const float* __restrict__ Q, float* __restrict__ S2,
    const float* __restrict__ logw, float* __restrict__ logZt) {
  __shared__ float4 part[4][32];
  __shared__ float wx[64];
  __shared__ float mTs[64][65];
  __shared__ float Zr[64];
  const int x = blockIdx.x;
  const int tid = threadIdx.x;
  if (x < 256) {
    const int b = x >> 5, ch = x & 31;
    const int g = tid >> 5, c4 = tid & 31;
    const float4* Q4 = (const float4*)(Q + (long)(b * QROWS + ch * 64 + 1) * NC);
    float4 acc = make_float4(0.f, 0.f, 0.f, 0.f);
#pragma unroll
    for (int i = 0; i < 16; ++i) {
      float4 v = Q4[(g * 16 + i) * 32 + c4];
      acc.x += v.x; acc.y += v.y; acc.z += v.z; acc.w += v.w;
    }
    part[g][c4] = acc;
    __syncthreads();
    if (g == 0) {
      float4 p0 = part[0][c4], p1 = part[1][c4], p2 = part[2][c4], p3 = part[3][c4];
      ((float4*)(S2 + (long)(b * NCH + ch) * NC))[c4] =
          make_float4(p0.x + p1.x + p2.x + p3.x, p0.y + p1.y + p2.y + p3.y,
                      p0.z + p1.z + p2.z + p3.z, p0.w + p1.w + p2.w + p3.w);
    }
  } else {
    const int s = x - 256;
    const int j = tid;
    if (j < 64) wx[j] = __expf(logw[s * NLM + j]);
    __syncthreads();
    if (j < 64) {
      float q[4][16];
      tri_scan64([&](int t, int l) { return wx[l]; },
                 [&](int t) { int l = t + j; return (l < 64) ? wx[l] : 0.f; }, q);
#pragma unroll
      for (int tau = 0; tau < 4; ++tau)
#pragma unroll
        for (int i = 0; i < 16; ++i) mTs[j][tau * 16 + i] = q[tau][i];
    }
    const int t = j;
    if (t < 64) Zr[t] = (t == 0) ? 1.f : 0.f;
    if (t == 0) logZt[s * QROWS] = 0.f;
    float off = 0.f;
    __syncthreads();
    for (int ch = 0; ch < NCH; ++ch) {
      float acc = 0.f, mx = 0.f;
      if (t < 64) {
#pragma unroll 8
        for (int jj = 0; jj < 64; ++jj) acc = fmaf(mTs[jj][t], Zr[jj], acc);
        logZt[s * QROWS + ch * 64 + 1 + t] = logf(acc) + off;
        mx = acc;
#pragma unroll
        for (int o = 32; o; o >>= 1) mx = fmaxf(mx, __shfl_xor(mx, o));
      }
      __syncthreads();
      if (t < 64) {
        Zr[63 - t] = acc / mx;
        off += logf(mx);
      }
      __syncthreads();
    }
  }
}

// KB merged: blocks 0..127 = k5a_basis (per s,ch: pi softmax in-LDS ->
//   global pi; impulse-response R -> rt; history responses -> ctT; klocal);
//   blocks 128..383 = k2c (prefix fixup of Q).
__global__ __launch_bounds__(128) void kb_basis_fix(
    const float* __restrict__ logw, const float* __restrict__ logZt,
    float* __restrict__ pig, float* __restrict__ rt, float* __restrict__ ctT,
    float* __restrict__ klocal, float* __restrict__ Q,
    const float* __restrict__ S2) {
  __shared__ __align__(16) float psd[4096];
  __shared__ float Rl[64][65];
  __shared__ float lzs[128];
  __shared__ float lws[64];
  __shared__ float4 gsum[4][32];
  const int x = blockIdx.x;
  const int tid = threadIdx.x;
  if (x < 128) {
    const int s = x >> 5, ch = x & 31;
    {
      int idx = ch * 64 - 63 + tid;
      lzs[tid] = (idx >= 0) ? logZt[s * QROWS + idx] : -INFINITY;
      if (tid < 64) lws[tid] = logw[s * NLM + tid];
    }
    __syncthreads();
    {
      const int l = tid & 63, wv = tid >> 6;
      for (int tt = wv; tt < 64; tt += 2) {
        float la = lws[l] + lzs[tt + 63 - l];
        float m = la;
#pragma unroll
        for (int o = 32; o; o >>= 1) m = fmaxf(m, __shfl_xor(m, o));
        float p = __expf(la - m);
        float zs = p;
#pragma unroll
        for (int o = 32; o; o >>= 1) zs += __shfl_xor(zs, o);
        float pv = p * rcp_fast(zs);
        psd[tt * 64 + l] = pv;
        pig[((long)s * NT + ch * 64 + tt) * NLM + l] = pv;
      }
    }
    __syncthreads();
    float q[4][16];
    if (tid < 64) {
      const int tp = tid;  // impulse position
      tri_scan64([&](int t, int l) { return psd[t * 64 + l]; },
                 [&](int t) { return (t == tp) ? 1.f : 0.f; }, q);
      float* rrow = rt + (((long)s * NCH + ch) * 64 + tp) * 64;  // [tp][t]
#pragma unroll
      for (int tau = 0; tau < 4; ++tau)
#pragma unroll
        for (int i = 0; i < 16; ++i) {
          rrow[tau * 16 + i] = q[tau][i];
          Rl[tp][tau * 16 + i] = q[tau][i];
        }
    } else {
      const int j = tid - 64;  // history lookback j+1
      tri_scan64([&](int t, int l) { return psd[t * 64 + l]; },
                 [&](int t) { int l = t + j; return (l < 64) ? psd[t * 64 + l] : 0.f; }, q);
      float* ctb = ctT + ((long)s * NCH + ch) * 4096;  // [t][j]
#pragma unroll
      for (int tau = 0; tau < 4; ++tau)
#pragma unroll
        for (int i = 0; i < 16; ++i) ctb[(tau * 16 + i) * 64 + j] = q[tau][i];
    }
    __syncthreads();
    if (tid < 64) {  // klocal[t] = sum_t' R[t][t']
      float acc = 0.f;
#pragma unroll 8
      for (int tp = 0; tp < 64; ++tp) acc += Rl[tp][tid];
      klocal[((long)s * NCH + ch) * 64 + tid] = acc;
    }
  } else {
    const int y = x - 128;
    const int b = y >> 5, ch = y & 31;
    const int g = tid >> 5, c4 = tid & 31;
    if (ch == 0 && g == 0)
      ((float4*)(Q + (long)(b * QROWS) * NC))[c4] = make_float4(0.f, 0.f, 0.f, 0.f);
    float4 run = make_float4(0.f, 0.f, 0.f, 0.f);
    for (int i = 0; i < ch; ++i) {
      float4 v = ((const float4*)(S2 + (long)(b * NCH + i) * NC))[c4];
      run.x += v.x; run.y += v.y; run.z += v.z; run.w += v.w;
    }
    float4* Q4 = (float4*)(Q + (long)(b * QROWS + ch * 64 + 1) * NC);
    {
      float4 gs = make_float4(0.f, 0.f, 0.f, 0.f);
#pragma unroll
      for (int i = 0; i < 16; ++i) {
        float4 v = Q4[(g * 16 + i) * 32 + c4];
        gs.x += v.x; gs.y += v.y; gs.z += v.z; gs.w += v.w;
      }
      gsum[g][c4] = gs;
    }
    __syncthreads();
    for (int gp = 0; gp < 3; ++gp) {
      if (gp < g) {
        float4 v = gsum[gp][c4];
        run.x += v.x; run.y += v.y; run.z += v.z; run.w += v.w;
      }
    }
#pragma unroll 4
    for (int i = 0; i < 16; ++i) {
      float4* p = Q4 + (g * 16 + i) * 32 + c4;
      float4 v = *p;
      run.x += v.x; run.y += v.y; run.z += v.z; run.w += v.w;
      *p = run;
    }
  }
}

// K4: e[s,b,ti,c] = 1 - 2 * sum_l pi[s,ti,l] * rcp(exp2(y)+1)
__global__ __launch_bounds__(256) void k4_e(
    const float* __restrict__ Q, const float* __restrict__ pi,
    const float* __restrict__ phib, float* __restrict__ eq) {
  __shared__ float Qw[80][64];                   // 20 KB
  __shared__ __align__(16) float ps[4][16][64];  // 16 KB
  const int b = blockIdx.x;
  const int t0 = blockIdx.y * 16;
  const int half = blockIdx.z;
  const int tid = threadIdx.x;
  for (int i = tid; i < 80 * 64; i += 256) {
    int r = i >> 6, cc = i & 63;
    int tau = t0 - 63 + r;
    Qw[r][cc] = (tau >= 0) ? Q[(b * QROWS + tau) * NC + half * 64 + cc] : 0.f;
  }
  for (int i = tid; i < 1024; i += 256) {  // 1024 float4 = 4 scales x 256
    int s = i >> 8, rem = i & 255;
    ((float4*)ps)[i] = ((const float4*)(pi + ((long)s * NT + t0) * NLM))[rem];
  }
  __syncthreads();
  const int c = tid & 63, tg = tid >> 6;  // tg wave-uniform
  const float pb2 = phib[half * 64 + c] * TWO_LOG2E;
  for (int tt = tg; tt < 16; tt += 4) {
    const int ti = t0 + tt;
    const float Qt = Qw[tt + 64][c];
    float a0 = 0.f, a1 = 0.f, a2 = 0.f, a3 = 0.f;
#pragma unroll
    for (int l = 0; l < 64; l += 4) {
      float v[4];
#pragma unroll
      for (int u = 0; u < 4; ++u) {
        const float cl = TWO_LOG2E / (float)(l + u + 9);  // folded constant
        float y = (Qt - Qw[tt + 63 - (l + u)][c]) * cl + pb2;
        v[u] = rcp_fast(__builtin_exp2f(y) + 1.f);
      }
      float4 w0 = *(const float4*)&ps[0][tt][l];
      float4 w1 = *(const float4*)&ps[1][tt][l];
      float4 w2 = *(const float4*)&ps[2][tt][l];
      float4 w3 = *(const float4*)&ps[3][tt][l];
      a0 = fmaf(w0.x, v[0], a0); a0 = fmaf(w0.y, v[1], a0);
      a0 = fmaf(w0.z, v[2], a0); a0 = fmaf(w0.w, v[3], a0);
      a1 = fmaf(w1.x, v[0], a1); a1 = fmaf(w1.y, v[1], a1);
      a1 = fmaf(w1.z, v[2], a1); a1 = fmaf(w1.w, v[3], a1);
      a2 = fmaf(w2.x, v[0], a2); a2 = fmaf(w2.y, v[1], a2);
      a2 = fmaf(w2.z, v[2], a2); a2 = fmaf(w2.w, v[3], a2);
      a3 = fmaf(w3.x, v[0], a3); a3 = fmaf(w3.y, v[1], a3);
      a3 = fmaf(w3.z, v[2], a3); a3 = fmaf(w3.w, v[3], a3);
    }
    const long base = half * 64 + c;
    eq[((long)(0 * 8 + b) * NT + ti) * NC + base] = fmaf(-2.f, a0, 1.f);
    eq[((long)(1 * 8 + b) * NT + ti) * NC + base] = fmaf(-2.f, a1, 1.f);
    eq[((long)(2 * 8 + b) * NT + ti) * NC + base] = fmaf(-2.f, a2, 1.f);
    eq[((long)(3 * 8 + b) * NT + ti) * NC + base] = fmaf(-2.f, a3, 1.f);
  }
}

// K5a-data: qlocal = R @ e per (s,b,chunk) — tiled GEMM, 8t x 8c per lane.
__global__ __launch_bounds__(128) void k5a_data(const float* __restrict__ rt,
                                                float* __restrict__ eq) {
  __shared__ __align__(16) float rts[4096];    // [tp][t] 16 KB
  __shared__ __align__(16) float es[64][128];  // 32 KB
  const int sb = blockIdx.x;  // s*8+b
  const int s = sb >> 3;
  const int ch = blockIdx.y;
  const int tid = threadIdx.x;
  const float4* rsrc = (const float4*)(rt + ((long)s * NCH + ch) * 4096);
#pragma unroll
  for (int i = 0; i < 8; ++i) ((float4*)rts)[tid + 128 * i] = rsrc[tid + 128 * i];
  float* qb = eq + ((long)sb * NT + ch * 64) * NC;
  const float4* esrc = (const float4*)qb;
#pragma unroll
  for (int i = 0; i < 16; ++i) ((float4*)es)[tid + 128 * i] = esrc[tid + 128 * i];
  __syncthreads();
  const int t0 = (tid >> 4) * 8;  // 8 t-tiles
  const int c0 = (tid & 15) * 8;  // 16 c-tiles
  float acc[8][8];
#pragma unroll
  for (int i = 0; i < 8; ++i)
#pragma unroll
    for (int k = 0; k < 8; ++k) acc[i][k] = 0.f;
  for (int tp = 0; tp < 64; ++tp) {
    if (tp <= t0 + 7) {  // R is lower-triangular
      float4 r0 = *(const float4*)&rts[tp * 64 + t0];
      float4 r1 = *(const float4*)&rts[tp * 64 + t0 + 4];
      float4 e0 = *(const float4*)&es[tp][c0];
      float4 e1 = *(const float4*)&es[tp][c0 + 4];
      float rr[8] = {r0.x, r0.y, r0.z, r0.w, r1.x, r1.y, r1.z, r1.w};
      float ee[8] = {e0.x, e0.y, e0.z, e0.w, e1.x, e1.y, e1.z, e1.w};
#pragma unroll
      for (int i = 0; i < 8; ++i)
#pragma unroll
        for (int k = 0; k < 8; ++k) acc[i][k] = fmaf(rr[i], ee[k], acc[i][k]);
    }
  }
#pragma unroll
  for (int i = 0; i < 8; ++i) {
    float4* dst = (float4*)(qb + (t0 + i) * NC + c0);
    dst[0] = make_float4(acc[i][0], acc[i][1], acc[i][2], acc[i][3]);
    dst[1] = make_float4(acc[i][4], acc[i][5], acc[i][6], acc[i][7]);
  }
}

// K5b: cross-chunk combine, no LDS: history in the wave's own registers via
// v_readlane (compile-time lanes). 256 q-blocks x 2 waves: each wave owns one
// 8-channel slice; both waves share s -> identical ctT addresses (L1 hits) and
// double the in-flight bytes per CU. XCD swizzle: blockIdx.x % 8 == {2s,2s+1},
// clustering each s's 512 KB ctT working set into 2 XCD L2s (R9 showed ~40 MB
// of HBM ctT re-fetch when spread across all 8). Plain loads/stores (R9's
// nontemporal raised WRITE 33->43 MB and regressed).
// Blocks 256..259: k cross-chunk combine (per s), wave 0 only.
__global__ __launch_bounds__(128) void k5b_scan(const float* __restrict__ ctT,
                                                const float* __restrict__ klocal,
                                                float* __restrict__ eq,
                                                float* __restrict__ kout) {
  const int tid = threadIdx.x;
  const int t = tid & 63;
  if (blockIdx.x < 256) {
    const int e = blockIdx.x & 7, g = blockIdx.x >> 3;
    const int s = e >> 1, hp = e & 1;
    const int b = g & 7, pp = g >> 3;
    const int w = tid >> 6;
    const int sl = ((pp << 1) | hp) * 2 + w;  // 0..15
    const int c0 = sl * 8;
    const int sb = s * 8 + b;
    const float* ctTs = ctT + (long)s * NCH * 4096 + t * 64;
    float* eqb = eq + (long)sb * NT * NC + c0;
    float4 crA[16], crB[16];
    {
      const float4* p = (const float4*)ctTs;
#pragma unroll
      for (int i = 0; i < 16; ++i) crA[i] = p[i];
    }
    float4 qlA0 = ((const float4*)(eqb + t * NC))[0];
    float4 qlA1 = ((const float4*)(eqb + t * NC))[1];
    float4 qlB0, qlB1;
    float hv[8];
#pragma unroll
    for (int i = 0; i < 8; ++i) hv[i] = 0.f;

#define K5B_BODY(CH, CR, QL0, QL1)                                           \
    {                                                                        \
      float acc[8];                                                          \
      _Pragma("unroll") for (int i = 0; i < 8; ++i) acc[i] = 0.f;            \
      const float* cr = (const float*)(CR);                                  \
      _Pragma("unroll") for (int j = 0; j < 64; ++j) {                       \
        float cv = cr[j];                                                    \
        _Pragma("unroll") for (int i = 0; i < 8; ++i)                        \
            acc[i] = fmaf(cv, readlane_f(hv[i], 63 - j), acc[i]);            \
      }                                                                      \
      hv[0] = acc[0] + (QL0).x; hv[1] = acc[1] + (QL0).y;                    \
      hv[2] = acc[2] + (QL0).z; hv[3] = acc[3] + (QL0).w;                    \
      hv[4] = acc[4] + (QL1).x; hv[5] = acc[5] + (QL1).y;                    \
      hv[6] = acc[6] + (QL1).z; hv[7] = acc[7] + (QL1).w;                    \
      float4* qp = (float4*)(eqb + ((CH) * 64 + t) * NC);                    \
      qp[0] = make_float4(hv[0], hv[1], hv[2], hv[3]);                       \
      qp[1] = make_float4(hv[4], hv[5], hv[6], hv[7]);                       \
    }

#pragma unroll 1
    for (int ch = 0; ch < NCH; ch += 2) {
      {
        const float4* p = (const float4*)(ctTs + (ch + 1) * 4096);
#pragma unroll
        for (int i = 0; i < 16; ++i) crB[i] = p[i];
        const float4* qn = (const float4*)(eqb + ((ch + 1) * 64 + t) * NC);
        qlB0 = qn[0];
        qlB1 = qn[1];
      }
      K5B_BODY(ch, crA, qlA0, qlA1)
      if (ch + 2 < NCH) {
        const float4* p = (const float4*)(ctTs + (ch + 2) * 4096);
#pragma unroll
        for (int i = 0; i < 16; ++i) crA[i] = p[i];
        const float4* qn = (const float4*)(eqb + ((ch + 2) * 64 + t) * NC);
        qlA0 = qn[0];
        qlA1 = qn[1];
      }
      K5B_BODY(ch + 1, crB, qlB0, qlB1)
    }
#undef K5B_BODY
  } else if (tid < 64) {
    const int s = blockIdx.x - 256;
    const float* ctTs = ctT + (long)s * NCH * 4096 + t * 64;
    const float* klb = klocal + (long)s * NCH * 64 + t;
    float4 crA[16], crB[16];
    {
      const float4* p = (const float4*)ctTs;
#pragma unroll
      for (int i = 0; i < 16; ++i) crA[i] = p[i];
    }
    float klA = klb[0], klB;
    float hk = 0.f;

#define K5BK_BODY(CH, CR, KL)                                                \
    {                                                                        \
      float acc = (KL);                                                      \
      const float* cr = (const float*)(CR);                                  \
      _Pragma("unroll") for (int j = 0; j < 64; ++j)                         \
          acc = fmaf(cr[j], readlane_f(hk, 63 - j), acc);                    \
      kout[s * NT + (CH) * 64 + t] = acc;                                    \
      hk = acc;                                                              \
    }

#pragma unroll 1
    for (int ch = 0; ch < NCH; ch += 2) {
      {
        const float4* p = (const float4*)(ctTs + (ch + 1) * 4096);
#pragma unroll
        for (int i = 0; i < 16; ++i) crB[i] = p[i];
        klB = klb[(ch + 1) * 64];
      }
      K5BK_BODY(ch, crA, klA)
      if (ch + 2 < NCH) {
        const float4* p = (const float4*)(ctTs + (ch + 2) * 4096);
#pragma unroll
        for (int i = 0; i < 16; ++i) crA[i] = p[i];
        klA = klb[(ch + 2) * 64];
      }
      K5BK_BODY(ch + 1, crB, klB)
    }
#undef K5BK_BODY
  }
}

// K6: rep = (q + 16*anchor)/(k+16) * (k/(k+16)); out = rep_flat @ mix_w + mix_b
__global__ __launch_bounds__(256) void k6_mix(
    const float* __restrict__ q, const float* __restrict__ kout,
    const float* __restrict__ anchor, const float* __restrict__ mixw,
    const float* __restrict__ mixb, float* __restrict__ out) {
  __shared__ __align__(16) float rsdata[16][512];  // 32 KB
  const int b = blockIdx.x;
  const int t0 = blockIdx.y * 16;
  const int tid = threadIdx.x;
  for (int i = tid; i < 16 * 512; i += 256) {
    int r = i >> 9, sc = i & 511;
    int s = sc >> 7, c = sc & 127;
    int ti = t0 + r;
    float qv = q[((long)(s * 8 + b) * NT + ti) * NC + c];
    float kv = kout[s * NT + ti];
    float d1 = rcp_fast(kv + 16.f);
    rsdata[r][sc] = (qv + 16.f * anchor[sc]) * d1 * (kv * d1);
  }
  __syncthreads();
  const int co = tid & 127, hf = tid >> 7;
  const int r0 = hf * 8;
  float mb = mixb[co];
  float acc[8];
#pragma unroll
  for (int r = 0; r < 8; ++r) acc[r] = mb;
  for (int kk = 0; kk < 512; kk += 4) {
    float wa = mixw[(kk + 0) * 128 + co];
    float wb = mixw[(kk + 1) * 128 + co];
    float wc = mixw[(kk + 2) * 128 + co];
    float wd = mixw[(kk + 3) * 128 + co];
#pragma unroll
    for (int r = 0; r < 8; ++r) {
      float4 rv = *(const float4*)&rsdata[r0 + r][kk];
      acc[r] = fmaf(rv.x, wa, acc[r]);
      acc[r] = fmaf(rv.y, wb, acc[r]);
      acc[r] = fmaf(rv.z, wc, acc[r]);
      acc[r] = fmaf(rv.w, wd, acc[r]);
    }
  }
#pragma unroll
  for (int r = 0; r < 8; ++r)
    out[((long)b * NT + t0 + r0 + r) * NC + co] = acc[r];
}

extern "C" void kernel_launch(void* const* d_in, const int* in_sizes, int n_in,
                              void* d_out, int out_size, void* d_ws, size_t ws_size,
                              hipStream_t stream) {
  const float* x = (const float*)d_in[0];
  const float* W = (const float*)d_in[1];
  const float* bias = (const float*)d_in[2];
  const float* phiw = (const float*)d_in[3];
  const float* phib = (const float*)d_in[4];
  const float* anchor = (const float*)d_in[5];
  const float* logw = (const float*)d_in[6];
  const float* mixw = (const float*)d_in[7];
  const float* mixb = (const float*)d_in[8];
  float* out = (float*)d_out;

  float* ws = (float*)d_ws;
  float* Q = ws;                                     // 8*2049*128 = 2,098,176
  float* pi = Q + (long)NB * QROWS * NC;             // 4*2048*64  =   524,288
  float* eq = pi + (long)NS * NT * NLM;              // 32*2048*128= 8,388,608
  float* coefTT = eq + (long)NS * NB * NT * NC;      //               524,288
  float* rtb = coefTT + (long)NS * NCH * 4096;       //               524,288
  float* klocal = rtb + (long)NS * NCH * 4096;       //                 8,192
  float* kout = klocal + (long)NS * NCH * 64;        //                 8,192
  float* logZt = kout + (long)NS * NT;               //                 8,196
  float* S2 = logZt + (long)NS * QROWS;              //                32,768

  hipLaunchKernelGGL(k1_uv, dim3(NB * NT / 16), dim3(128), 0, stream, x, W, bias, phiw, Q);
  hipLaunchKernelGGL(k23_sums_logz, dim3(260), dim3(128), 0, stream, Q, S2, logw, logZt);
  hipLaunchKernelGGL(kb_basis_fix, dim3(384), dim3(128), 0, stream, logw, logZt, pi, rtb, coefTT, klocal, Q, S2);
  hipLaunchKernelGGL(k4_e, dim3(NB, NT / 16, 2), dim3(256), 0, stream, Q, pi, phib, eq);
  hipLaunchKernelGGL(k5a_data, dim3(NS * NB, NCH), dim3(128), 0, stream, rtb, eq);
  hipLaunchKernelGGL(k5b_scan, dim3(260), dim3(128), 0, stream, coefTT, klocal, eq, kout);
  hipLaunchKernelGGL(k6_mix, dim3(NB, NT / 16), dim3(256), 0, stream, eq, kout, anchor, mixw, mixb, out);
}

// Round 11
// 446.863 us; speedup vs baseline: 1.1239x; 1.0168x over previous
//
#include <hip/hip_runtime.h>
#include <math.h>

// Problem constants
#define NB 8
#define NT 2048
#define NC 128
#define NLM 64
#define NS 4
#define QROWS 2049
#define NCH 32  // 2048 / 64 chunks

#define TWO_LOG2E 2.885390081777927f

__device__ __forceinline__ float rcp_fast(float x) {
  return __builtin_amdgcn_rcpf(x);
}

__device__ __forceinline__ float readlane_f(float v, int lane) {
  return __int_as_float(__builtin_amdgcn_readlane(__float_as_int(v), lane));
}

// ---------------------------------------------------------------------------
// Tiled 64-step local linear scan (forward substitution); all indices
// compile-time so q[4][16] stays in VGPRs. (Used by k23's logZ branch.)
// ---------------------------------------------------------------------------
template <typename PF, typename DF>
__device__ __forceinline__ void tri_scan64(PF P, DF D, float q[4][16]) {
#pragma unroll
  for (int tau = 0; tau < 4; ++tau) {
    float acc[16];
#pragma unroll
    for (int i = 0; i < 16; ++i) acc[i] = D(tau * 16 + i);
#pragma unroll
    for (int p = 0; p < 4; ++p) {
      if (p < tau) {
#pragma unroll
        for (int i = 0; i < 16; ++i) {
          const int t = tau * 16 + i;
#pragma unroll
          for (int i2 = 0; i2 < 16; ++i2) {
            acc[i] = fmaf(P(t, t - (p * 16 + i2) - 1), q[p][i2], acc[i]);
          }
        }
      }
    }
#pragma unroll
    for (int i = 0; i < 16; ++i) {
      const int t = tau * 16 + i;
#pragma unroll
      for (int i2 = 0; i2 < 16; ++i2) {
        if (i2 < i) acc[i] = fmaf(P(t, i - i2 - 1), q[tau][i2], acc[i]);
      }
      q[tau][i] = acc[i];
    }
  }
}

// ---------------------------------------------------------------------------
// Flat forward substitution over transposed-layout Pt[t][t'] (LDS, row stride
// 64): qv[t] = D(t) + sum_{t'<t} Pt[t][t'] qv[t'].
// Reads are ds_read_b128 row quads (R10's scalar descending reads were ~2000
// exposed-latency b32s at <1 wave/SIMD -> 86 us). 4 accumulator chains.
// ---------------------------------------------------------------------------
template <typename DF>
__device__ __forceinline__ void tri_scan64_flat(const float* Pt, DF D,
                                                float qv[64]) {
#pragma unroll
  for (int t = 0; t < 64; ++t) {
    float a0 = D(t), a1 = 0.f, a2 = 0.f, a3 = 0.f;
#pragma unroll
    for (int qd = 0; qd < 16; ++qd) {
      if (qd * 4 < t) {
        float4 p4 = *(const float4*)&Pt[t * 64 + qd * 4];
        a0 = fmaf(p4.x, qv[4 * qd + 0], a0);
        if (4 * qd + 1 < t) a1 = fmaf(p4.y, qv[4 * qd + 1], a1);
        if (4 * qd + 2 < t) a2 = fmaf(p4.z, qv[4 * qd + 2], a2);
        if (4 * qd + 3 < t) a3 = fmaf(p4.w, qv[4 * qd + 3], a3);
      }
    }
    qv[t] = (a0 + a1) + (a2 + a3);
  }
}

// K1: per 16 rows (b,t): z = x@W + b ; u = [cos,sin]/sqrt(dh) ; V = u @ phi_w
__global__ __launch_bounds__(128) void k1_uv(
    const float* __restrict__ x, const float* __restrict__ W,
    const float* __restrict__ bias, const float* __restrict__ phiw,
    float* __restrict__ Q) {
  __shared__ __align__(16) float xs[16][128];  // 8 KB
  __shared__ float us[16][256];                // 16 KB
  const int j = threadIdx.x;
  const int bt0 = blockIdx.x * 16;
  {
    const float4* x4 = (const float4*)(x + (long)bt0 * NC);
#pragma unroll
    for (int i = 0; i < 4; ++i)
      ((float4*)xs)[j + 128 * i] = x4[j + 128 * i];
  }
  __syncthreads();
  float z[16];
  const float bj = bias[j];
#pragma unroll
  for (int r = 0; r < 16; ++r) z[r] = bj;
  for (int k = 0; k < 128; ++k) {
    float w = W[k * 128 + j];
#pragma unroll
    for (int r = 0; r < 16; ++r) z[r] = fmaf(xs[r][k], w, z[r]);
  }
  const float rs = 0.08838834764831845f;  // 1/sqrt(128)
#pragma unroll
  for (int r = 0; r < 16; ++r) {
    float sv, cv;
    sincosf(z[r], &sv, &cv);
    us[r][j] = cv * rs;
    us[r][128 + j] = sv * rs;
  }
  __syncthreads();
  float a[16];
#pragma unroll
  for (int r = 0; r < 16; ++r) a[r] = 0.f;
  for (int k = 0; k < 256; ++k) {
    float w = phiw[k * 128 + j];
#pragma unroll
    for (int r = 0; r < 16; ++r) a[r] = fmaf(us[r][k], w, a[r]);
  }
#pragma unroll
  for (int r = 0; r < 16; ++r) {
    int bt = bt0 + r;
    int b = bt >> 11, t = bt & 2047;
    Q[(b * QROWS + t + 1) * NC + j] = a[r];
  }
}

// K23 merged: blocks 0..255 = k2a (per-chunk raw sums of V);
//             blocks 256..259 = k3ab (serial logZ chunk evolution, per s).
__global__ __launch_bounds__(128) void k23_sums_logz(
    const float* __restrict__ Q, float* __restrict__ S2,
    const float* __restrict__ logw, float* __restrict__ logZt) {
  __shared__ float4 part[4][32];
  __shared__ float wx[64];
  __shared__ float mTs[64][65];
  __shared__ float Zr[64];
  const int x = blockIdx.x;
  const int tid = threadIdx.x;
  if (x < 256) {
    const int b = x >> 5, ch = x & 31;
    const int g = tid >> 5, c4 = tid & 31;
    const float4* Q4 = (const float4*)(Q + (long)(b * QROWS + ch * 64 + 1) * NC);
    float4 acc = make_float4(0.f, 0.f, 0.f, 0.f);
#pragma unroll
    for (int i = 0; i < 16; ++i) {
      float4 v = Q4[(g * 16 + i) * 32 + c4];
      acc.x += v.x; acc.y += v.y; acc.z += v.z; acc.w += v.w;
    }
    part[g][c4] = acc;
    __syncthreads();
    if (g == 0) {
      float4 p0 = part[0][c4], p1 = part[1][c4], p2 = part[2][c4], p3 = part[3][c4];
      ((float4*)(S2 + (long)(b * NCH + ch) * NC))[c4] =
          make_float4(p0.x + p1.x + p2.x + p3.x, p0.y + p1.y + p2.y + p3.y,
                      p0.z + p1.z + p2.z + p3.z, p0.w + p1.w + p2.w + p3.w);
    }
  } else {
    const int s = x - 256;
    const int j = tid;
    if (j < 64) wx[j] = __expf(logw[s * NLM + j]);
    __syncthreads();
    if (j < 64) {
      float q[4][16];
      tri_scan64([&](int t, int l) { return wx[l]; },
                 [&](int t) { int l = t + j; return (l < 64) ? wx[l] : 0.f; }, q);
#pragma unroll
      for (int tau = 0; tau < 4; ++tau)
#pragma unroll
        for (int i = 0; i < 16; ++i) mTs[j][tau * 16 + i] = q[tau][i];
    }
    const int t = j;
    if (t < 64) Zr[t] = (t == 0) ? 1.f : 0.f;
    if (t == 0) logZt[s * QROWS] = 0.f;
    float off = 0.f;
    __syncthreads();
    for (int ch = 0; ch < NCH; ++ch) {
      float acc = 0.f, mx = 0.f;
      if (t < 64) {
#pragma unroll 8
        for (int jj = 0; jj < 64; ++jj) acc = fmaf(mTs[jj][t], Zr[jj], acc);
        logZt[s * QROWS + ch * 64 + 1 + t] = logf(acc) + off;
        mx = acc;
#pragma unroll
        for (int o = 32; o; o >>= 1) mx = fmaxf(mx, __shfl_xor(mx, o));
      }
      __syncthreads();
      if (t < 64) {
        Zr[63 - t] = acc / mx;
        off += logf(mx);
      }
      __syncthreads();
    }
  }
}

// KB merged: blocks 0..127 = k5a_basis (pi softmax in-LDS -> global pi;
//   impulse-response R -> rt; history responses -> ctT; klocal);
//   blocks 128..383 = k2c (prefix fixup of Q).
// Basis phase 1 uses the Pt transposed layout + tri_scan64_flat (b128 reads).
__global__ __launch_bounds__(128) void kb_basis_fix(
    const float* __restrict__ logw, const float* __restrict__ logZt,
    float* __restrict__ pig, float* __restrict__ rt, float* __restrict__ ctT,
    float* __restrict__ klocal, float* __restrict__ Q,
    const float* __restrict__ S2) {
  __shared__ __align__(16) float psd[4096];  // pi [t][l]       16 KB
  __shared__ __align__(16) float Pts[4096];  // Pt [t][t']      16 KB
  __shared__ float Rl[64][65];
  __shared__ float lzs[128];
  __shared__ float lws[64];
  __shared__ float4 gsum[4][32];
  const int x = blockIdx.x;
  const int tid = threadIdx.x;
  if (x < 128) {
    const int s = x >> 5, ch = x & 31;
    {
      int idx = ch * 64 - 63 + tid;
      lzs[tid] = (idx >= 0) ? logZt[s * QROWS + idx] : -INFINITY;
      if (tid < 64) lws[tid] = logw[s * NLM + tid];
    }
    __syncthreads();
    {
      const int l = tid & 63, wv = tid >> 6;
      for (int tt = wv; tt < 64; tt += 2) {
        float la = lws[l] + lzs[tt + 63 - l];
        float m = la;
#pragma unroll
        for (int o = 32; o; o >>= 1) m = fmaxf(m, __shfl_xor(m, o));
        float p = __expf(la - m);
        float zs = p;
#pragma unroll
        for (int o = 32; o; o >>= 1) zs += __shfl_xor(zs, o);
        float pv = p * rcp_fast(zs);
        psd[tt * 64 + l] = pv;
        pig[((long)s * NT + ch * 64 + tt) * NLM + l] = pv;
      }
    }
    __syncthreads();
    // build Pt[t][t'] = psd[t][t-t'-1] (t'<t), else 0
    for (int i = tid; i < 4096; i += 128) {
      int t = i >> 6, tp = i & 63;
      Pts[i] = (tp < t) ? psd[t * 64 + (t - tp - 1)] : 0.f;
    }
    __syncthreads();
    float qv[64];
    if (tid < 64) {
      const int tp = tid;  // impulse position
      tri_scan64_flat(Pts, [&](int t) { return (t == tp) ? 1.f : 0.f; }, qv);
      float* rrow = rt + (((long)s * NCH + ch) * 64 + tp) * 64;  // [tp][t]
#pragma unroll
      for (int t4 = 0; t4 < 16; ++t4)
        ((float4*)rrow)[t4] = make_float4(qv[4 * t4], qv[4 * t4 + 1],
                                          qv[4 * t4 + 2], qv[4 * t4 + 3]);
#pragma unroll
      for (int t = 0; t < 64; ++t) Rl[tp][t] = qv[t];
    } else {
      const int j = tid - 64;  // history lookback j+1
      tri_scan64_flat(
          Pts, [&](int t) { int l = t + j; return (l < 64) ? psd[t * 64 + l] : 0.f; },
          qv);
      float* ctb = ctT + ((long)s * NCH + ch) * 4096;  // [t][j]
#pragma unroll
      for (int t = 0; t < 64; ++t) ctb[t * 64 + j] = qv[t];
    }
    __syncthreads();
    if (tid < 64) {  // klocal[t] = sum_tp R[t][tp]
      float acc = 0.f;
#pragma unroll 8
      for (int tp = 0; tp < 64; ++tp) acc += Rl[tp][tid];
      klocal[((long)s * NCH + ch) * 64 + tid] = acc;
    }
  } else {
    const int y = x - 128;
    const int b = y >> 5, ch = y & 31;
    const int g = tid >> 5, c4 = tid & 31;
    if (ch == 0 && g == 0)
      ((float4*)(Q + (long)(b * QROWS) * NC))[c4] = make_float4(0.f, 0.f, 0.f, 0.f);
    float4 run = make_float4(0.f, 0.f, 0.f, 0.f);
    for (int i = 0; i < ch; ++i) {
      float4 v = ((const float4*)(S2 + (long)(b * NCH + i) * NC))[c4];
      run.x += v.x; run.y += v.y; run.z += v.z; run.w += v.w;
    }
    float4* Q4 = (float4*)(Q + (long)(b * QROWS + ch * 64 + 1) * NC);
    {
      float4 gs = make_float4(0.f, 0.f, 0.f, 0.f);
#pragma unroll
      for (int i = 0; i < 16; ++i) {
        float4 v = Q4[(g * 16 + i) * 32 + c4];
        gs.x += v.x; gs.y += v.y; gs.z += v.z; gs.w += v.w;
      }
      gsum[g][c4] = gs;
    }
    __syncthreads();
    for (int gp = 0; gp < 3; ++gp) {
      if (gp < g) {
        float4 v = gsum[gp][c4];
        run.x += v.x; run.y += v.y; run.z += v.z; run.w += v.w;
      }
    }
#pragma unroll 4
    for (int i = 0; i < 16; ++i) {
      float4* p = Q4 + (g * 16 + i) * 32 + c4;
      float4 v = *p;
      run.x += v.x; run.y += v.y; run.z += v.z; run.w += v.w;
      *p = run;
    }
  }
}

// K4: e[s,b,ti,c] = 1 - 2 * sum_l pi[s,ti,l] * rcp(exp2(y)+1)
__global__ __launch_bounds__(256) void k4_e(
    const float* __restrict__ Q, const float* __restrict__ pi,
    const float* __restrict__ phib, float* __restrict__ eq) {
  __shared__ float Qw[80][64];                   // 20 KB
  __shared__ __align__(16) float ps[4][16][64];  // 16 KB
  const int b = blockIdx.x;
  const int t0 = blockIdx.y * 16;
  const int half = blockIdx.z;
  const int tid = threadIdx.x;
  for (int i = tid; i < 80 * 64; i += 256) {
    int r = i >> 6, cc = i & 63;
    int tau = t0 - 63 + r;
    Qw[r][cc] = (tau >= 0) ? Q[(b * QROWS + tau) * NC + half * 64 + cc] : 0.f;
  }
  for (int i = tid; i < 1024; i += 256) {  // 1024 float4 = 4 scales x 256
    int s = i >> 8, rem = i & 255;
    ((float4*)ps)[i] = ((const float4*)(pi + ((long)s * NT + t0) * NLM))[rem];
  }
  __syncthreads();
  const int c = tid & 63, tg = tid >> 6;  // tg wave-uniform
  const float pb2 = phib[half * 64 + c] * TWO_LOG2E;
  for (int tt = tg; tt < 16; tt += 4) {
    const int ti = t0 + tt;
    const float Qt = Qw[tt + 64][c];
    float a0 = 0.f, a1 = 0.f, a2 = 0.f, a3 = 0.f;
#pragma unroll
    for (int l = 0; l < 64; l += 4) {
      float v[4];
#pragma unroll
      for (int u = 0; u < 4; ++u) {
        const float cl = TWO_LOG2E / (float)(l + u + 9);  // folded constant
        float y = (Qt - Qw[tt + 63 - (l + u)][c]) * cl + pb2;
        v[u] = rcp_fast(__builtin_exp2f(y) + 1.f);
      }
      float4 w0 = *(const float4*)&ps[0][tt][l];
      float4 w1 = *(const float4*)&ps[1][tt][l];
      float4 w2 = *(const float4*)&ps[2][tt][l];
      float4 w3 = *(const float4*)&ps[3][tt][l];
      a0 = fmaf(w0.x, v[0], a0); a0 = fmaf(w0.y, v[1], a0);
      a0 = fmaf(w0.z, v[2], a0); a0 = fmaf(w0.w, v[3], a0);
      a1 = fmaf(w1.x, v[0], a1); a1 = fmaf(w1.y, v[1], a1);
      a1 = fmaf(w1.z, v[2], a1); a1 = fmaf(w1.w, v[3], a1);
      a2 = fmaf(w2.x, v[0], a2); a2 = fmaf(w2.y, v[1], a2);
      a2 = fmaf(w2.z, v[2], a2); a2 = fmaf(w2.w, v[3], a2);
      a3 = fmaf(w3.x, v[0], a3); a3 = fmaf(w3.y, v[1], a3);
      a3 = fmaf(w3.z, v[2], a3); a3 = fmaf(w3.w, v[3], a3);
    }
    const long base = half * 64 + c;
    eq[((long)(0 * 8 + b) * NT + ti) * NC + base] = fmaf(-2.f, a0, 1.f);
    eq[((long)(1 * 8 + b) * NT + ti) * NC + base] = fmaf(-2.f, a1, 1.f);
    eq[((long)(2 * 8 + b) * NT + ti) * NC + base] = fmaf(-2.f, a2, 1.f);
    eq[((long)(3 * 8 + b) * NT + ti) * NC + base] = fmaf(-2.f, a3, 1.f);
  }
}

// K5a-data: qlocal = R @ e per (s,b,chunk) — tiled GEMM, 8t x 8c per lane.
__global__ __launch_bounds__(128) void k5a_data(const float* __restrict__ rt,
                                                float* __restrict__ eq) {
  __shared__ __align__(16) float rts[4096];    // [tp][t] 16 KB
  __shared__ __align__(16) float es[64][128];  // 32 KB
  const int sb = blockIdx.x;  // s*8+b
  const int s = sb >> 3;
  const int ch = blockIdx.y;
  const int tid = threadIdx.x;
  const float4* rsrc = (const float4*)(rt + ((long)s * NCH + ch) * 4096);
#pragma unroll
  for (int i = 0; i < 8; ++i) ((float4*)rts)[tid + 128 * i] = rsrc[tid + 128 * i];
  float* qb = eq + ((long)sb * NT + ch * 64) * NC;
  const float4* esrc = (const float4*)qb;
#pragma unroll
  for (int i = 0; i < 16; ++i) ((float4*)es)[tid + 128 * i] = esrc[tid + 128 * i];
  __syncthreads();
  const int t0 = (tid >> 4) * 8;  // 8 t-tiles
  const int c0 = (tid & 15) * 8;  // 16 c-tiles
  float acc[8][8];
#pragma unroll
  for (int i = 0; i < 8; ++i)
#pragma unroll
    for (int k = 0; k < 8; ++k) acc[i][k] = 0.f;
  for (int tp = 0; tp < 64; ++tp) {
    if (tp <= t0 + 7) {  // R is lower-triangular
      float4 r0 = *(const float4*)&rts[tp * 64 + t0];
      float4 r1 = *(const float4*)&rts[tp * 64 + t0 + 4];
      float4 e0 = *(const float4*)&es[tp][c0];
      float4 e1 = *(const float4*)&es[tp][c0 + 4];
      float rr[8] = {r0.x, r0.y, r0.z, r0.w, r1.x, r1.y, r1.z, r1.w};
      float ee[8] = {e0.x, e0.y, e0.z, e0.w, e1.x, e1.y, e1.z, e1.w};
#pragma unroll
      for (int i = 0; i < 8; ++i)
#pragma unroll
        for (int k = 0; k < 8; ++k) acc[i][k] = fmaf(rr[i], ee[k], acc[i][k]);
    }
  }
#pragma unroll
  for (int i = 0; i < 8; ++i) {
    float4* dst = (float4*)(qb + (t0 + i) * NC + c0);
    dst[0] = make_float4(acc[i][0], acc[i][1], acc[i][2], acc[i][3]);
    dst[1] = make_float4(acc[i][4], acc[i][5], acc[i][6], acc[i][7]);
  }
}

// K5b: cross-chunk combine, no LDS: history in the wave's own registers via
// v_readlane. 256 q-blocks x 2 waves (shared s -> L1 ctT hits); XCD swizzle
// blockIdx.x % 8 == {2s,2s+1}. Plain loads/stores.
// Blocks 256..259: k cross-chunk combine (per s), wave 0 only.
__global__ __launch_bounds__(128) void k5b_scan(const float* __restrict__ ctT,
                                                const float* __restrict__ klocal,
                                                float* __restrict__ eq,
                                                float* __restrict__ kout) {
  const int tid = threadIdx.x;
  const int t = tid & 63;
  if (blockIdx.x < 256) {
    const int e = blockIdx.x & 7, g = blockIdx.x >> 3;
    const int s = e >> 1, hp = e & 1;
    const int b = g & 7, pp = g >> 3;
    const int w = tid >> 6;
    const int sl = ((pp << 1) | hp) * 2 + w;  // 0..15
    const int c0 = sl * 8;
    const int sb = s * 8 + b;
    const float* ctTs = ctT + (long)s * NCH * 4096 + t * 64;
    float* eqb = eq + (long)sb * NT * NC + c0;
    float4 crA[16], crB[16];
    {
      const float4* p = (const float4*)ctTs;
#pragma unroll
      for (int i = 0; i < 16; ++i) crA[i] = p[i];
    }
    float4 qlA0 = ((const float4*)(eqb + t * NC))[0];
    float4 qlA1 = ((const float4*)(eqb + t * NC))[1];
    float4 qlB0, qlB1;
    float hv[8];
#pragma unroll
    for (int i = 0; i < 8; ++i) hv[i] = 0.f;

#define K5B_BODY(CH, CR, QL0, QL1)                                           \
    {                                                                        \
      float acc[8];                                                          \
      _Pragma("unroll") for (int i = 0; i < 8; ++i) acc[i] = 0.f;            \
      const float* cr = (const float*)(CR);                                  \
      _Pragma("unroll") for (int j = 0; j < 64; ++j) {                       \
        float cv = cr[j];                                                    \
        _Pragma("unroll") for (int i = 0; i < 8; ++i)                        \
            acc[i] = fmaf(cv, readlane_f(hv[i], 63 - j), acc[i]);            \
      }                                                                      \
      hv[0] = acc[0] + (QL0).x; hv[1] = acc[1] + (QL0).y;                    \
      hv[2] = acc[2] + (QL0).z; hv[3] = acc[3] + (QL0).w;                    \
      hv[4] = acc[4] + (QL1).x; hv[5] = acc[5] + (QL1).y;                    \
      hv[6] = acc[6] + (QL1).z; hv[7] = acc[7] + (QL1).w;                    \
      float4* qp = (float4*)(eqb + ((CH) * 64 + t) * NC);                    \
      qp[0] = make_float4(hv[0], hv[1], hv[2], hv[3]);                       \
      qp[1] = make_float4(hv[4], hv[5], hv[6], hv[7]);                       \
    }

#pragma unroll 1
    for (int ch = 0; ch < NCH; ch += 2) {
      {
        const float4* p = (const float4*)(ctTs + (ch + 1) * 4096);
#pragma unroll
        for (int i = 0; i < 16; ++i) crB[i] = p[i];
        const float4* qn = (const float4*)(eqb + ((ch + 1) * 64 + t) * NC);
        qlB0 = qn[0];
        qlB1 = qn[1];
      }
      K5B_BODY(ch, crA, qlA0, qlA1)
      if (ch + 2 < NCH) {
        const float4* p = (const float4*)(ctTs + (ch + 2) * 4096);
#pragma unroll
        for (int i = 0; i < 16; ++i) crA[i] = p[i];
        const float4* qn = (const float4*)(eqb + ((ch + 2) * 64 + t) * NC);
        qlA0 = qn[0];
        qlA1 = qn[1];
      }
      K5B_BODY(ch + 1, crB, qlB0, qlB1)
    }
#undef K5B_BODY
  } else if (tid < 64) {
    const int s = blockIdx.x - 256;
    const float* ctTs = ctT + (long)s * NCH * 4096 + t * 64;
    const float* klb = klocal + (long)s * NCH * 64 + t;
    float4 crA[16], crB[16];
    {
      const float4* p = (const float4*)ctTs;
#pragma unroll
      for (int i = 0; i < 16; ++i) crA[i] = p[i];
    }
    float klA = klb[0], klB;
    float hk = 0.f;

#define K5BK_BODY(CH, CR, KL)                                                \
    {                                                                        \
      float acc = (KL);                                                      \
      const float* cr = (const float*)(CR);                                  \
      _Pragma("unroll") for (int j = 0; j < 64; ++j)                         \
          acc = fmaf(cr[j], readlane_f(hk, 63 - j), acc);                    \
      kout[s * NT + (CH) * 64 + t] = acc;                                    \
      hk = acc;                                                              \
    }

#pragma unroll 1
    for (int ch = 0; ch < NCH; ch += 2) {
      {
        const float4* p = (const float4*)(ctTs + (ch + 1) * 4096);
#pragma unroll
        for (int i = 0; i < 16; ++i) crB[i] = p[i];
        klB = klb[(ch + 1) * 64];
      }
      K5BK_BODY(ch, crA, klA)
      if (ch + 2 < NCH) {
        const float4* p = (const float4*)(ctTs + (ch + 2) * 4096);
#pragma unroll
        for (int i = 0; i < 16; ++i) crA[i] = p[i];
        klA = klb[(ch + 2) * 64];
      }
      K5BK_BODY(ch + 1, crB, klB)
    }
#undef K5BK_BODY
  }
}

// K6: rep = (q + 16*anchor)/(k+16) * (k/(k+16)); out = rep_flat @ mix_w + mix_b
__global__ __launch_bounds__(256) void k6_mix(
    const float* __restrict__ q, const float* __restrict__ kout,
    const float* __restrict__ anchor, const float* __restrict__ mixw,
    const float* __restrict__ mixb, float* __restrict__ out) {
  __shared__ __align__(16) float rsdata[16][512];  // 32 KB
  const int b = blockIdx.x;
  const int t0 = blockIdx.y * 16;
  const int tid = threadIdx.x;
  for (int i = tid; i < 16 * 512; i += 256) {
    int r = i >> 9, sc = i & 511;
    int s = sc >> 7, c = sc & 127;
    int ti = t0 + r;
    float qv = q[((long)(s * 8 + b) * NT + ti) * NC + c];
    float kv = kout[s * NT + ti];
    float d1 = rcp_fast(kv + 16.f);
    rsdata[r][sc] = (qv + 16.f * anchor[sc]) * d1 * (kv * d1);
  }
  __syncthreads();
  const int co = tid & 127, hf = tid >> 7;
  const int r0 = hf * 8;
  float mb = mixb[co];
  float acc[8];
#pragma unroll
  for (int r = 0; r < 8; ++r) acc[r] = mb;
  for (int kk = 0; kk < 512; kk += 4) {
    float wa = mixw[(kk + 0) * 128 + co];
    float wb = mixw[(kk + 1) * 128 + co];
    float wc = mixw[(kk + 2) * 128 + co];
    float wd = mixw[(kk + 3) * 128 + co];
#pragma unroll
    for (int r = 0; r < 8; ++r) {
      float4 rv = *(const float4*)&rsdata[r0 + r][kk];
      acc[r] = fmaf(rv.x, wa, acc[r]);
      acc[r] = fmaf(rv.y, wb, acc[r]);
      acc[r] = fmaf(rv.z, wc, acc[r]);
      acc[r] = fmaf(rv.w, wd, acc[r]);
    }
  }
#pragma unroll
  for (int r = 0; r < 8; ++r)
    out[((long)b * NT + t0 + r0 + r) * NC + co] = acc[r];
}

extern "C" void kernel_launch(void* const* d_in, const int* in_sizes, int n_in,
                              void* d_out, int out_size, void* d_ws, size_t ws_size,
                              hipStream_t stream) {
  const float* x = (const float*)d_in[0];
  const float* W = (const float*)d_in[1];
  const float* bias = (const float*)d_in[2];
  const float* phiw = (const float*)d_in[3];
  const float* phib = (const float*)d_in[4];
  const float* anchor = (const float*)d_in[5];
  const float* logw = (const float*)d_in[6];
  const float* mixw = (const float*)d_in[7];
  const float* mixb = (const float*)d_in[8];
  float* out = (float*)d_out;

  float* ws = (float*)d_ws;
  float* Q = ws;                                     // 8*2049*128 = 2,098,176
  float* pi = Q + (long)NB * QROWS * NC;             // 4*2048*64  =   524,288
  float* eq = pi + (long)NS * NT * NLM;              // 32*2048*128= 8,388,608
  float* coefTT = eq + (long)NS * NB * NT * NC;      //               524,288
  float* rtb = coefTT + (long)NS * NCH * 4096;       //               524,288
  float* klocal = rtb + (long)NS * NCH * 4096;       //                 8,192
  float* kout = klocal + (long)NS * NCH * 64;        //                 8,192
  float* logZt = kout + (long)NS * NT;               //                 8,196
  float* S2 = logZt + (long)NS * QROWS;              //                32,768

  hipLaunchKernelGGL(k1_uv, dim3(NB * NT / 16), dim3(128), 0, stream, x, W, bias, phiw, Q);
  hipLaunchKernelGGL(k23_sums_logz, dim3(260), dim3(128), 0, stream, Q, S2, logw, logZt);
  hipLaunchKernelGGL(kb_basis_fix, dim3(384), dim3(128), 0, stream, logw, logZt, pi, rtb, coefTT, klocal, Q, S2);
  hipLaunchKernelGGL(k4_e, dim3(NB, NT / 16, 2), dim3(256), 0, stream, Q, pi, phib, eq);
  hipLaunchKernelGGL(k5a_data, dim3(NS * NB, NCH), dim3(128), 0, stream, rtb, eq);
  hipLaunchKernelGGL(k5b_scan, dim3(260), dim3(128), 0, stream, coefTT, klocal, eq, kout);
  hipLaunchKernelGGL(k6_mix, dim3(NB, NT / 16), dim3(256), 0, stream, eq, kout, anchor, mixw, mixb, out);
}

// Round 12
// 442.592 us; speedup vs baseline: 1.1347x; 1.0096x over previous
//
#include <hip/hip_runtime.h>
#include <math.h>

// Problem constants
#define NB 8
#define NT 2048
#define NC 128
#define NLM 64
#define NS 4
#define QROWS 2049
#define NCH 32  // 2048 / 64 chunks

#define TWO_LOG2E 2.885390081777927f

__device__ __forceinline__ float rcp_fast(float x) {
  return __builtin_amdgcn_rcpf(x);
}

__device__ __forceinline__ float readlane_f(float v, int lane) {
  return __int_as_float(__builtin_amdgcn_readlane(__float_as_int(v), lane));
}

// ---------------------------------------------------------------------------
// Tiled 64-step local linear scan (forward substitution); all indices
// compile-time so q[4][16] stays in VGPRs. (Used by k23's logZ branch.)
// ---------------------------------------------------------------------------
template <typename PF, typename DF>
__device__ __forceinline__ void tri_scan64(PF P, DF D, float q[4][16]) {
#pragma unroll
  for (int tau = 0; tau < 4; ++tau) {
    float acc[16];
#pragma unroll
    for (int i = 0; i < 16; ++i) acc[i] = D(tau * 16 + i);
#pragma unroll
    for (int p = 0; p < 4; ++p) {
      if (p < tau) {
#pragma unroll
        for (int i = 0; i < 16; ++i) {
          const int t = tau * 16 + i;
#pragma unroll
          for (int i2 = 0; i2 < 16; ++i2) {
            acc[i] = fmaf(P(t, t - (p * 16 + i2) - 1), q[p][i2], acc[i]);
          }
        }
      }
    }
#pragma unroll
    for (int i = 0; i < 16; ++i) {
      const int t = tau * 16 + i;
#pragma unroll
      for (int i2 = 0; i2 < 16; ++i2) {
        if (i2 < i) acc[i] = fmaf(P(t, i - i2 - 1), q[tau][i2], acc[i]);
      }
      q[tau][i] = acc[i];
    }
  }
}

// K1: per 16 rows (b,t): z = x@W + b ; u = [cos,sin]/sqrt(dh) ; V = u @ phi_w
__global__ __launch_bounds__(128) void k1_uv(
    const float* __restrict__ x, const float* __restrict__ W,
    const float* __restrict__ bias, const float* __restrict__ phiw,
    float* __restrict__ Q) {
  __shared__ __align__(16) float xs[16][128];  // 8 KB
  __shared__ float us[16][256];                // 16 KB
  const int j = threadIdx.x;
  const int bt0 = blockIdx.x * 16;
  {
    const float4* x4 = (const float4*)(x + (long)bt0 * NC);
#pragma unroll
    for (int i = 0; i < 4; ++i)
      ((float4*)xs)[j + 128 * i] = x4[j + 128 * i];
  }
  __syncthreads();
  float z[16];
  const float bj = bias[j];
#pragma unroll
  for (int r = 0; r < 16; ++r) z[r] = bj;
  for (int k = 0; k < 128; ++k) {
    float w = W[k * 128 + j];
#pragma unroll
    for (int r = 0; r < 16; ++r) z[r] = fmaf(xs[r][k], w, z[r]);
  }
  const float rs = 0.08838834764831845f;  // 1/sqrt(128)
#pragma unroll
  for (int r = 0; r < 16; ++r) {
    float sv, cv;
    sincosf(z[r], &sv, &cv);
    us[r][j] = cv * rs;
    us[r][128 + j] = sv * rs;
  }
  __syncthreads();
  float a[16];
#pragma unroll
  for (int r = 0; r < 16; ++r) a[r] = 0.f;
  for (int k = 0; k < 256; ++k) {
    float w = phiw[k * 128 + j];
#pragma unroll
    for (int r = 0; r < 16; ++r) a[r] = fmaf(us[r][k], w, a[r]);
  }
#pragma unroll
  for (int r = 0; r < 16; ++r) {
    int bt = bt0 + r;
    int b = bt >> 11, t = bt & 2047;
    Q[(b * QROWS + t + 1) * NC + j] = a[r];
  }
}

// K23 merged: blocks 0..255 = k2a (per-chunk raw sums of V);
//             blocks 256..259 = k3ab (serial logZ chunk evolution, per s).
__global__ __launch_bounds__(128) void k23_sums_logz(
    const float* __restrict__ Q, float* __restrict__ S2,
    const float* __restrict__ logw, float* __restrict__ logZt) {
  __shared__ float4 part[4][32];
  __shared__ float wx[64];
  __shared__ float mTs[64][65];
  __shared__ float Zr[64];
  const int x = blockIdx.x;
  const int tid = threadIdx.x;
  if (x < 256) {
    const int b = x >> 5, ch = x & 31;
    const int g = tid >> 5, c4 = tid & 31;
    const float4* Q4 = (const float4*)(Q + (long)(b * QROWS + ch * 64 + 1) * NC);
    float4 acc = make_float4(0.f, 0.f, 0.f, 0.f);
#pragma unroll
    for (int i = 0; i < 16; ++i) {
      float4 v = Q4[(g * 16 + i) * 32 + c4];
      acc.x += v.x; acc.y += v.y; acc.z += v.z; acc.w += v.w;
    }
    part[g][c4] = acc;
    __syncthreads();
    if (g == 0) {
      float4 p0 = part[0][c4], p1 = part[1][c4], p2 = part[2][c4], p3 = part[3][c4];
      ((float4*)(S2 + (long)(b * NCH + ch) * NC))[c4] =
          make_float4(p0.x + p1.x + p2.x + p3.x, p0.y + p1.y + p2.y + p3.y,
                      p0.z + p1.z + p2.z + p3.z, p0.w + p1.w + p2.w + p3.w);
    }
  } else {
    const int s = x - 256;
    const int j = tid;
    if (j < 64) wx[j] = __expf(logw[s * NLM + j]);
    __syncthreads();
    if (j < 64) {
      float q[4][16];
      tri_scan64([&](int t, int l) { return wx[l]; },
                 [&](int t) { int l = t + j; return (l < 64) ? wx[l] : 0.f; }, q);
#pragma unroll
      for (int tau = 0; tau < 4; ++tau)
#pragma unroll
        for (int i = 0; i < 16; ++i) mTs[j][tau * 16 + i] = q[tau][i];
    }
    const int t = j;
    if (t < 64) Zr[t] = (t == 0) ? 1.f : 0.f;
    if (t == 0) logZt[s * QROWS] = 0.f;
    float off = 0.f;
    __syncthreads();
    for (int ch = 0; ch < NCH; ++ch) {
      float acc = 0.f, mx = 0.f;
      if (t < 64) {
#pragma unroll 8
        for (int jj = 0; jj < 64; ++jj) acc = fmaf(mTs[jj][t], Zr[jj], acc);
        logZt[s * QROWS + ch * 64 + 1 + t] = logf(acc) + off;
        mx = acc;
#pragma unroll
        for (int o = 32; o; o >>= 1) mx = fmaxf(mx, __shfl_xor(mx, o));
      }
      __syncthreads();
      if (t < 64) {
        Zr[63 - t] = acc / mx;
        off += logf(mx);
      }
      __syncthreads();
    }
  }
}

// KB merged: blocks 0..127 = k5a_basis; blocks 128..383 = k2c (prefix fixup).
// Basis now runs ONE unrolled scan body for all 128 threads (R11 had two ~20KB
// instantiations — one per wave — thrashing the 32KB I$; data-path rewrites
// didn't move the 84 us, pointing at instruction fetch). D columns come from
// LDS: Dl[t][tid] = identity col (tid<64) or history col (tid-64).
__global__ __launch_bounds__(128) void kb_basis_fix(
    const float* __restrict__ logw, const float* __restrict__ logZt,
    float* __restrict__ pig, float* __restrict__ rt, float* __restrict__ ctT,
    float* __restrict__ klocal, float* __restrict__ Q,
    const float* __restrict__ S2) {
  // sbuf: [0,4096) psd (pi [t][l]); [4096,8192) Pts (Pt [t][t']);
  //       [8192,16384) Dl ([t][u], u=0..127). After the scan, Rl (stride 65,
  //       4160 floats) aliases [0,8192).
  __shared__ __align__(16) float sbuf[16384];  // 64 KB
  __shared__ float lzs[128];
  __shared__ float lws[64];
  __shared__ float4 gsum[4][32];
  float* psd = sbuf;
  float* Pts = sbuf + 4096;
  float* Dl = sbuf + 8192;
  float* Rl = sbuf;  // stride 65, valid after scan barrier
  const int x = blockIdx.x;
  const int tid = threadIdx.x;
  if (x < 128) {
    const int s = x >> 5, ch = x & 31;
    {
      int idx = ch * 64 - 63 + tid;
      lzs[tid] = (idx >= 0) ? logZt[s * QROWS + idx] : -INFINITY;
      if (tid < 64) lws[tid] = logw[s * NLM + tid];
    }
    __syncthreads();
    {
      const int l = tid & 63, wv = tid >> 6;
      for (int tt = wv; tt < 64; tt += 2) {
        float la = lws[l] + lzs[tt + 63 - l];
        float m = la;
#pragma unroll
        for (int o = 32; o; o >>= 1) m = fmaxf(m, __shfl_xor(m, o));
        float p = __expf(la - m);
        float zs = p;
#pragma unroll
        for (int o = 32; o; o >>= 1) zs += __shfl_xor(zs, o);
        float pv = p * rcp_fast(zs);
        psd[tt * 64 + l] = pv;
        pig[((long)s * NT + ch * 64 + tt) * NLM + l] = pv;
      }
    }
    __syncthreads();
    // Pt[t][t'] = psd[t][t-t'-1] (t'<t) else 0  (32 elems/thread)
    for (int i = tid; i < 4096; i += 128) {
      int t = i >> 6, tp = i & 63;
      Pts[i] = (tp < t) ? psd[t * 64 + (t - tp - 1)] : 0.f;
    }
    // Dl[t][u]: u<64 identity col u; u>=64 history col j=u-64 (64 elems/thread)
    for (int i = tid; i < 8192; i += 128) {
      int t = i >> 7, u = i & 127;
      float d;
      if (u < 64) {
        d = (t == u) ? 1.f : 0.f;
      } else {
        int l = t + (u - 64);
        d = (l < 64) ? psd[t * 64 + l] : 0.f;
      }
      Dl[i] = d;
    }
    __syncthreads();
    // unified flat forward substitution (single instantiation, both waves)
    float qv[64];
    const float* Dcol = Dl + tid;
#pragma unroll
    for (int t = 0; t < 64; ++t) {
      float a0 = Dcol[t * 128], a1 = 0.f, a2 = 0.f, a3 = 0.f;
#pragma unroll
      for (int qd = 0; qd < 16; ++qd) {
        if (qd * 4 < t) {
          float4 p4 = *(const float4*)&Pts[t * 64 + qd * 4];
          a0 = fmaf(p4.x, qv[4 * qd + 0], a0);
          if (4 * qd + 1 < t) a1 = fmaf(p4.y, qv[4 * qd + 1], a1);
          if (4 * qd + 2 < t) a2 = fmaf(p4.z, qv[4 * qd + 2], a2);
          if (4 * qd + 3 < t) a3 = fmaf(p4.w, qv[4 * qd + 3], a3);
        }
      }
      qv[t] = (a0 + a1) + (a2 + a3);
    }
    __syncthreads();  // psd/Pts dead; Rl may now alias them
    if (tid < 64) {
      const int tp = tid;  // impulse column
      float* rrow = rt + (((long)s * NCH + ch) * 64 + tp) * 64;  // [tp][t]
#pragma unroll
      for (int t4 = 0; t4 < 16; ++t4)
        ((float4*)rrow)[t4] = make_float4(qv[4 * t4], qv[4 * t4 + 1],
                                          qv[4 * t4 + 2], qv[4 * t4 + 3]);
#pragma unroll
      for (int t = 0; t < 64; ++t) Rl[tp * 65 + t] = qv[t];
    } else {
      const int j = tid - 64;  // history lookback j+1
      float* ctb = ctT + ((long)s * NCH + ch) * 4096;  // [t][j]
#pragma unroll
      for (int t = 0; t < 64; ++t) ctb[t * 64 + j] = qv[t];
    }
    __syncthreads();
    if (tid < 64) {  // klocal[t] = sum_tp R[t][tp]
      float acc = 0.f;
#pragma unroll 8
      for (int tp = 0; tp < 64; ++tp) acc += Rl[tp * 65 + tid];
      klocal[((long)s * NCH + ch) * 64 + tid] = acc;
    }
  } else {
    const int y = x - 128;
    const int b = y >> 5, ch = y & 31;
    const int g = tid >> 5, c4 = tid & 31;
    if (ch == 0 && g == 0)
      ((float4*)(Q + (long)(b * QROWS) * NC))[c4] = make_float4(0.f, 0.f, 0.f, 0.f);
    float4 run = make_float4(0.f, 0.f, 0.f, 0.f);
    for (int i = 0; i < ch; ++i) {
      float4 v = ((const float4*)(S2 + (long)(b * NCH + i) * NC))[c4];
      run.x += v.x; run.y += v.y; run.z += v.z; run.w += v.w;
    }
    float4* Q4 = (float4*)(Q + (long)(b * QROWS + ch * 64 + 1) * NC);
    // single read of Q (R11 read twice); independent loads -> pipelined
    float4 vbuf[16];
#pragma unroll
    for (int i = 0; i < 16; ++i) vbuf[i] = Q4[(g * 16 + i) * 32 + c4];
    {
      float4 gs = make_float4(0.f, 0.f, 0.f, 0.f);
#pragma unroll
      for (int i = 0; i < 16; ++i) {
        gs.x += vbuf[i].x; gs.y += vbuf[i].y; gs.z += vbuf[i].z; gs.w += vbuf[i].w;
      }
      gsum[g][c4] = gs;
    }
    __syncthreads();
    for (int gp = 0; gp < 3; ++gp) {
      if (gp < g) {
        float4 v = gsum[gp][c4];
        run.x += v.x; run.y += v.y; run.z += v.z; run.w += v.w;
      }
    }
#pragma unroll
    for (int i = 0; i < 16; ++i) {
      run.x += vbuf[i].x; run.y += vbuf[i].y; run.z += vbuf[i].z; run.w += vbuf[i].w;
      Q4[(g * 16 + i) * 32 + c4] = run;
    }
  }
}

// K4: e[s,b,ti,c] = 1 - 2 * sum_l pi[s,ti,l] * rcp(exp2(y)+1)
__global__ __launch_bounds__(256) void k4_e(
    const float* __restrict__ Q, const float* __restrict__ pi,
    const float* __restrict__ phib, float* __restrict__ eq) {
  __shared__ float Qw[80][64];                   // 20 KB
  __shared__ __align__(16) float ps[4][16][64];  // 16 KB
  const int b = blockIdx.x;
  const int t0 = blockIdx.y * 16;
  const int half = blockIdx.z;
  const int tid = threadIdx.x;
  for (int i = tid; i < 80 * 64; i += 256) {
    int r = i >> 6, cc = i & 63;
    int tau = t0 - 63 + r;
    Qw[r][cc] = (tau >= 0) ? Q[(b * QROWS + tau) * NC + half * 64 + cc] : 0.f;
  }
  for (int i = tid; i < 1024; i += 256) {  // 1024 float4 = 4 scales x 256
    int s = i >> 8, rem = i & 255;
    ((float4*)ps)[i] = ((const float4*)(pi + ((long)s * NT + t0) * NLM))[rem];
  }
  __syncthreads();
  const int c = tid & 63, tg = tid >> 6;  // tg wave-uniform
  const float pb2 = phib[half * 64 + c] * TWO_LOG2E;
  for (int tt = tg; tt < 16; tt += 4) {
    const int ti = t0 + tt;
    const float Qt = Qw[tt + 64][c];
    float a0 = 0.f, a1 = 0.f, a2 = 0.f, a3 = 0.f;
#pragma unroll
    for (int l = 0; l < 64; l += 4) {
      float v[4];
#pragma unroll
      for (int u = 0; u < 4; ++u) {
        const float cl = TWO_LOG2E / (float)(l + u + 9);  // folded constant
        float y = (Qt - Qw[tt + 63 - (l + u)][c]) * cl + pb2;
        v[u] = rcp_fast(__builtin_exp2f(y) + 1.f);
      }
      float4 w0 = *(const float4*)&ps[0][tt][l];
      float4 w1 = *(const float4*)&ps[1][tt][l];
      float4 w2 = *(const float4*)&ps[2][tt][l];
      float4 w3 = *(const float4*)&ps[3][tt][l];
      a0 = fmaf(w0.x, v[0], a0); a0 = fmaf(w0.y, v[1], a0);
      a0 = fmaf(w0.z, v[2], a0); a0 = fmaf(w0.w, v[3], a0);
      a1 = fmaf(w1.x, v[0], a1); a1 = fmaf(w1.y, v[1], a1);
      a1 = fmaf(w1.z, v[2], a1); a1 = fmaf(w1.w, v[3], a1);
      a2 = fmaf(w2.x, v[0], a2); a2 = fmaf(w2.y, v[1], a2);
      a2 = fmaf(w2.z, v[2], a2); a2 = fmaf(w2.w, v[3], a2);
      a3 = fmaf(w3.x, v[0], a3); a3 = fmaf(w3.y, v[1], a3);
      a3 = fmaf(w3.z, v[2], a3); a3 = fmaf(w3.w, v[3], a3);
    }
    const long base = half * 64 + c;
    eq[((long)(0 * 8 + b) * NT + ti) * NC + base] = fmaf(-2.f, a0, 1.f);
    eq[((long)(1 * 8 + b) * NT + ti) * NC + base] = fmaf(-2.f, a1, 1.f);
    eq[((long)(2 * 8 + b) * NT + ti) * NC + base] = fmaf(-2.f, a2, 1.f);
    eq[((long)(3 * 8 + b) * NT + ti) * NC + base] = fmaf(-2.f, a3, 1.f);
  }
}

// K5a-data: qlocal = R @ e per (s,b,chunk) — tiled GEMM, 8t x 8c per lane.
__global__ __launch_bounds__(128) void k5a_data(const float* __restrict__ rt,
                                                float* __restrict__ eq) {
  __shared__ __align__(16) float rts[4096];    // [tp][t] 16 KB
  __shared__ __align__(16) float es[64][128];  // 32 KB
  const int sb = blockIdx.x;  // s*8+b
  const int s = sb >> 3;
  const int ch = blockIdx.y;
  const int tid = threadIdx.x;
  const float4* rsrc = (const float4*)(rt + ((long)s * NCH + ch) * 4096);
#pragma unroll
  for (int i = 0; i < 8; ++i) ((float4*)rts)[tid + 128 * i] = rsrc[tid + 128 * i];
  float* qb = eq + ((long)sb * NT + ch * 64) * NC;
  const float4* esrc = (const float4*)qb;
#pragma unroll
  for (int i = 0; i < 16; ++i) ((float4*)es)[tid + 128 * i] = esrc[tid + 128 * i];
  __syncthreads();
  const int t0 = (tid >> 4) * 8;  // 8 t-tiles
  const int c0 = (tid & 15) * 8;  // 16 c-tiles
  float acc[8][8];
#pragma unroll
  for (int i = 0; i < 8; ++i)
#pragma unroll
    for (int k = 0; k < 8; ++k) acc[i][k] = 0.f;
  for (int tp = 0; tp < 64; ++tp) {
    if (tp <= t0 + 7) {  // R is lower-triangular
      float4 r0 = *(const float4*)&rts[tp * 64 + t0];
      float4 r1 = *(const float4*)&rts[tp * 64 + t0 + 4];
      float4 e0 = *(const float4*)&es[tp][c0];
      float4 e1 = *(const float4*)&es[tp][c0 + 4];
      float rr[8] = {r0.x, r0.y, r0.z, r0.w, r1.x, r1.y, r1.z, r1.w};
      float ee[8] = {e0.x, e0.y, e0.z, e0.w, e1.x, e1.y, e1.z, e1.w};
#pragma unroll
      for (int i = 0; i < 8; ++i)
#pragma unroll
        for (int k = 0; k < 8; ++k) acc[i][k] = fmaf(rr[i], ee[k], acc[i][k]);
    }
  }
#pragma unroll
  for (int i = 0; i < 8; ++i) {
    float4* dst = (float4*)(qb + (t0 + i) * NC + c0);
    dst[0] = make_float4(acc[i][0], acc[i][1], acc[i][2], acc[i][3]);
    dst[1] = make_float4(acc[i][4], acc[i][5], acc[i][6], acc[i][7]);
  }
}

// K5b: cross-chunk combine, no LDS: history in the wave's own registers via
// v_readlane. 256 q-blocks x 2 waves (shared s -> L1 ctT hits); XCD swizzle
// blockIdx.x % 8 == {2s,2s+1}. Plain loads/stores.
// Blocks 256..259: k cross-chunk combine (per s), wave 0 only.
__global__ __launch_bounds__(128) void k5b_scan(const float* __restrict__ ctT,
                                                const float* __restrict__ klocal,
                                                float* __restrict__ eq,
                                                float* __restrict__ kout) {
  const int tid = threadIdx.x;
  const int t = tid & 63;
  if (blockIdx.x < 256) {
    const int e = blockIdx.x & 7, g = blockIdx.x >> 3;
    const int s = e >> 1, hp = e & 1;
    const int b = g & 7, pp = g >> 3;
    const int w = tid >> 6;
    const int sl = ((pp << 1) | hp) * 2 + w;  // 0..15
    const int c0 = sl * 8;
    const int sb = s * 8 + b;
    const float* ctTs = ctT + (long)s * NCH * 4096 + t * 64;
    float* eqb = eq + (long)sb * NT * NC + c0;
    float4 crA[16], crB[16];
    {
      const float4* p = (const float4*)ctTs;
#pragma unroll
      for (int i = 0; i < 16; ++i) crA[i] = p[i];
    }
    float4 qlA0 = ((const float4*)(eqb + t * NC))[0];
    float4 qlA1 = ((const float4*)(eqb + t * NC))[1];
    float4 qlB0, qlB1;
    float hv[8];
#pragma unroll
    for (int i = 0; i < 8; ++i) hv[i] = 0.f;

#define K5B_BODY(CH, CR, QL0, QL1)                                           \
    {                                                                        \
      float acc[8];                                                          \
      _Pragma("unroll") for (int i = 0; i < 8; ++i) acc[i] = 0.f;            \
      const float* cr = (const float*)(CR);                                  \
      _Pragma("unroll") for (int j = 0; j < 64; ++j) {                       \
        float cv = cr[j];                                                    \
        _Pragma("unroll") for (int i = 0; i < 8; ++i)                        \
            acc[i] = fmaf(cv, readlane_f(hv[i], 63 - j), acc[i]);            \
      }                                                                      \
      hv[0] = acc[0] + (QL0).x; hv[1] = acc[1] + (QL0).y;                    \
      hv[2] = acc[2] + (QL0).z; hv[3] = acc[3] + (QL0).w;                    \
      hv[4] = acc[4] + (QL1).x; hv[5] = acc[5] + (QL1).y;                    \
      hv[6] = acc[6] + (QL1).z; hv[7] = acc[7] + (QL1).w;                    \
      float4* qp = (float4*)(eqb + ((CH) * 64 + t) * NC);                    \
      qp[0] = make_float4(hv[0], hv[1], hv[2], hv[3]);                       \
      qp[1] = make_float4(hv[4], hv[5], hv[6], hv[7]);                       \
    }

#pragma unroll 1
    for (int ch = 0; ch < NCH; ch += 2) {
      {
        const float4* p = (const float4*)(ctTs + (ch + 1) * 4096);
#pragma unroll
        for (int i = 0; i < 16; ++i) crB[i] = p[i];
        const float4* qn = (const float4*)(eqb + ((ch + 1) * 64 + t) * NC);
        qlB0 = qn[0];
        qlB1 = qn[1];
      }
      K5B_BODY(ch, crA, qlA0, qlA1)
      if (ch + 2 < NCH) {
        const float4* p = (const float4*)(ctTs + (ch + 2) * 4096);
#pragma unroll
        for (int i = 0; i < 16; ++i) crA[i] = p[i];
        const float4* qn = (const float4*)(eqb + ((ch + 2) * 64 + t) * NC);
        qlA0 = qn[0];
        qlA1 = qn[1];
      }
      K5B_BODY(ch + 1, crB, qlB0, qlB1)
    }
#undef K5B_BODY
  } else if (tid < 64) {
    const int s = blockIdx.x - 256;
    const float* ctTs = ctT + (long)s * NCH * 4096 + t * 64;
    const float* klb = klocal + (long)s * NCH * 64 + t;
    float4 crA[16], crB[16];
    {
      const float4* p = (const float4*)ctTs;
#pragma unroll
      for (int i = 0; i < 16; ++i) crA[i] = p[i];
    }
    float klA = klb[0], klB;
    float hk = 0.f;

#define K5BK_BODY(CH, CR, KL)                                                \
    {                                                                        \
      float acc = (KL);                                                      \
      const float* cr = (const float*)(CR);                                  \
      _Pragma("unroll") for (int j = 0; j < 64; ++j)                         \
          acc = fmaf(cr[j], readlane_f(hk, 63 - j), acc);                    \
      kout[s * NT + (CH) * 64 + t] = acc;                                    \
      hk = acc;                                                              \
    }

#pragma unroll 1
    for (int ch = 0; ch < NCH; ch += 2) {
      {
        const float4* p = (const float4*)(ctTs + (ch + 1) * 4096);
#pragma unroll
        for (int i = 0; i < 16; ++i) crB[i] = p[i];
        klB = klb[(ch + 1) * 64];
      }
      K5BK_BODY(ch, crA, klA)
      if (ch + 2 < NCH) {
        const float4* p = (const float4*)(ctTs + (ch + 2) * 4096);
#pragma unroll
        for (int i = 0; i < 16; ++i) crA[i] = p[i];
        klA = klb[(ch + 2) * 64];
      }
      K5BK_BODY(ch + 1, crB, klB)
    }
#undef K5BK_BODY
  }
}

// K6: rep = (q + 16*anchor)/(k+16) * (k/(k+16)); out = rep_flat @ mix_w + mix_b
__global__ __launch_bounds__(256) void k6_mix(
    const float* __restrict__ q, const float* __restrict__ kout,
    const float* __restrict__ anchor, const float* __restrict__ mixw,
    const float* __restrict__ mixb, float* __restrict__ out) {
  __shared__ __align__(16) float rsdata[16][512];  // 32 KB
  const int b = blockIdx.x;
  const int t0 = blockIdx.y * 16;
  const int tid = threadIdx.x;
  for (int i = tid; i < 16 * 512; i += 256) {
    int r = i >> 9, sc = i & 511;
    int s = sc >> 7, c = sc & 127;
    int ti = t0 + r;
    float qv = q[((long)(s * 8 + b) * NT + ti) * NC + c];
    float kv = kout[s * NT + ti];
    float d1 = rcp_fast(kv + 16.f);
    rsdata[r][sc] = (qv + 16.f * anchor[sc]) * d1 * (kv * d1);
  }
  __syncthreads();
  const int co = tid & 127, hf = tid >> 7;
  const int r0 = hf * 8;
  float mb = mixb[co];
  float acc[8];
#pragma unroll
  for (int r = 0; r < 8; ++r) acc[r] = mb;
  for (int kk = 0; kk < 512; kk += 4) {
    float wa = mixw[(kk + 0) * 128 + co];
    float wb = mixw[(kk + 1) * 128 + co];
    float wc = mixw[(kk + 2) * 128 + co];
    float wd = mixw[(kk + 3) * 128 + co];
#pragma unroll
    for (int r = 0; r < 8; ++r) {
      float4 rv = *(const float4*)&rsdata[r0 + r][kk];
      acc[r] = fmaf(rv.x, wa, acc[r]);
      acc[r] = fmaf(rv.y, wb, acc[r]);
      acc[r] = fmaf(rv.z, wc, acc[r]);
      acc[r] = fmaf(rv.w, wd, acc[r]);
    }
  }
#pragma unroll
  for (int r = 0; r < 8; ++r)
    out[((long)b * NT + t0 + r0 + r) * NC + co] = acc[r];
}

extern "C" void kernel_launch(void* const* d_in, const int* in_sizes, int n_in,
                              void* d_out, int out_size, void* d_ws, size_t ws_size,
                              hipStream_t stream) {
  const float* x = (const float*)d_in[0];
  const float* W = (const float*)d_in[1];
  const float* bias = (const float*)d_in[2];
  const float* phiw = (const float*)d_in[3];
  const float* phib = (const float*)d_in[4];
  const float* anchor = (const float*)d_in[5];
  const float* logw = (const float*)d_in[6];
  const float* mixw = (const float*)d_in[7];
  const float* mixb = (const float*)d_in[8];
  float* out = (float*)d_out;

  float* ws = (float*)d_ws;
  float* Q = ws;                                     // 8*2049*128 = 2,098,176
  float* pi = Q + (long)NB * QROWS * NC;             // 4*2048*64  =   524,288
  float* eq = pi + (long)NS * NT * NLM;              // 32*2048*128= 8,388,608
  float* coefTT = eq + (long)NS * NB * NT * NC;      //               524,288
  float* rtb = coefTT + (long)NS * NCH * 4096;       //               524,288
  float* klocal = rtb + (long)NS * NCH * 4096;       //                 8,192
  float* kout = klocal + (long)NS * NCH * 64;        //                 8,192
  float* logZt = kout + (long)NS * NT;               //                 8,196
  float* S2 = logZt + (long)NS * QROWS;              //                32,768

  hipLaunchKernelGGL(k1_uv, dim3(NB * NT / 16), dim3(128), 0, stream, x, W, bias, phiw, Q);
  hipLaunchKernelGGL(k23_sums_logz, dim3(260), dim3(128), 0, stream, Q, S2, logw, logZt);
  hipLaunchKernelGGL(kb_basis_fix, dim3(384), dim3(128), 0, stream, logw, logZt, pi, rtb, coefTT, klocal, Q, S2);
  hipLaunchKernelGGL(k4_e, dim3(NB, NT / 16, 2), dim3(256), 0, stream, Q, pi, phib, eq);
  hipLaunchKernelGGL(k5a_data, dim3(NS * NB, NCH), dim3(128), 0, stream, rtb, eq);
  hipLaunchKernelGGL(k5b_scan, dim3(260), dim3(128), 0, stream, coefTT, klocal, eq, kout);
  hipLaunchKernelGGL(k6_mix, dim3(NB, NT / 16), dim3(256), 0, stream, eq, kout, anchor, mixw, mixb, out);
}

// Round 13
// 429.182 us; speedup vs baseline: 1.1702x; 1.0312x over previous
//
#include <hip/hip_runtime.h>
#include <math.h>

// Problem constants
#define NB 8
#define NT 2048
#define NC 128
#define NLM 64
#define NS 4
#define QROWS 2049
#define NCH 32  // 2048 / 64 chunks

#define TWO_LOG2E 2.885390081777927f
#define LOG2E_F 1.4426950408889634f

__device__ __forceinline__ float rcp_fast(float x) {
  return __builtin_amdgcn_rcpf(x);
}

__device__ __forceinline__ float readlane_f(float v, int lane) {
  return __int_as_float(__builtin_amdgcn_readlane(__float_as_int(v), lane));
}

// ---------------------------------------------------------------------------
// Tiled 64-step local linear scan (forward substitution); all indices
// compile-time so q[4][16] stays in VGPRs. (Used by k23's logZ branch.)
// ---------------------------------------------------------------------------
template <typename PF, typename DF>
__device__ __forceinline__ void tri_scan64(PF P, DF D, float q[4][16]) {
#pragma unroll
  for (int tau = 0; tau < 4; ++tau) {
    float acc[16];
#pragma unroll
    for (int i = 0; i < 16; ++i) acc[i] = D(tau * 16 + i);
#pragma unroll
    for (int p = 0; p < 4; ++p) {
      if (p < tau) {
#pragma unroll
        for (int i = 0; i < 16; ++i) {
          const int t = tau * 16 + i;
#pragma unroll
          for (int i2 = 0; i2 < 16; ++i2) {
            acc[i] = fmaf(P(t, t - (p * 16 + i2) - 1), q[p][i2], acc[i]);
          }
        }
      }
    }
#pragma unroll
    for (int i = 0; i < 16; ++i) {
      const int t = tau * 16 + i;
#pragma unroll
      for (int i2 = 0; i2 < 16; ++i2) {
        if (i2 < i) acc[i] = fmaf(P(t, i - i2 - 1), q[tau][i2], acc[i]);
      }
      q[tau][i] = acc[i];
    }
  }
}

// K1: per 16 rows (b,t): z = x@W + b ; u = [cos,sin]/sqrt(dh) ; V = u @ phi_w
__global__ __launch_bounds__(128) void k1_uv(
    const float* __restrict__ x, const float* __restrict__ W,
    const float* __restrict__ bias, const float* __restrict__ phiw,
    float* __restrict__ Q) {
  __shared__ __align__(16) float xs[16][128];  // 8 KB
  __shared__ float us[16][256];                // 16 KB
  const int j = threadIdx.x;
  const int bt0 = blockIdx.x * 16;
  {
    const float4* x4 = (const float4*)(x + (long)bt0 * NC);
#pragma unroll
    for (int i = 0; i < 4; ++i)
      ((float4*)xs)[j + 128 * i] = x4[j + 128 * i];
  }
  __syncthreads();
  float z[16];
  const float bj = bias[j];
#pragma unroll
  for (int r = 0; r < 16; ++r) z[r] = bj;
  for (int k = 0; k < 128; ++k) {
    float w = W[k * 128 + j];
#pragma unroll
    for (int r = 0; r < 16; ++r) z[r] = fmaf(xs[r][k], w, z[r]);
  }
  const float rs = 0.08838834764831845f;  // 1/sqrt(128)
#pragma unroll
  for (int r = 0; r < 16; ++r) {
    float sv, cv;
    sincosf(z[r], &sv, &cv);
    us[r][j] = cv * rs;
    us[r][128 + j] = sv * rs;
  }
  __syncthreads();
  float a[16];
#pragma unroll
  for (int r = 0; r < 16; ++r) a[r] = 0.f;
  for (int k = 0; k < 256; ++k) {
    float w = phiw[k * 128 + j];
#pragma unroll
    for (int r = 0; r < 16; ++r) a[r] = fmaf(us[r][k], w, a[r]);
  }
#pragma unroll
  for (int r = 0; r < 16; ++r) {
    int bt = bt0 + r;
    int b = bt >> 11, t = bt & 2047;
    Q[(b * QROWS + t + 1) * NC + j] = a[r];
  }
}

// K23 merged: blocks 0..255 = k2a (per-chunk raw sums of V);
//             blocks 256..259 = k3ab (serial logZ chunk evolution, per s).
__global__ __launch_bounds__(128) void k23_sums_logz(
    const float* __restrict__ Q, float* __restrict__ S2,
    const float* __restrict__ logw, float* __restrict__ logZt) {
  __shared__ float4 part[4][32];
  __shared__ float wx[64];
  __shared__ float mTs[64][65];
  __shared__ float Zr[64];
  const int x = blockIdx.x;
  const int tid = threadIdx.x;
  if (x < 256) {
    const int b = x >> 5, ch = x & 31;
    const int g = tid >> 5, c4 = tid & 31;
    const float4* Q4 = (const float4*)(Q + (long)(b * QROWS + ch * 64 + 1) * NC);
    float4 acc = make_float4(0.f, 0.f, 0.f, 0.f);
#pragma unroll
    for (int i = 0; i < 16; ++i) {
      float4 v = Q4[(g * 16 + i) * 32 + c4];
      acc.x += v.x; acc.y += v.y; acc.z += v.z; acc.w += v.w;
    }
    part[g][c4] = acc;
    __syncthreads();
    if (g == 0) {
      float4 p0 = part[0][c4], p1 = part[1][c4], p2 = part[2][c4], p3 = part[3][c4];
      ((float4*)(S2 + (long)(b * NCH + ch) * NC))[c4] =
          make_float4(p0.x + p1.x + p2.x + p3.x, p0.y + p1.y + p2.y + p3.y,
                      p0.z + p1.z + p2.z + p3.z, p0.w + p1.w + p2.w + p3.w);
    }
  } else {
    const int s = x - 256;
    const int j = tid;
    if (j < 64) wx[j] = __expf(logw[s * NLM + j]);
    __syncthreads();
    if (j < 64) {
      float q[4][16];
      tri_scan64([&](int t, int l) { return wx[l]; },
                 [&](int t) { int l = t + j; return (l < 64) ? wx[l] : 0.f; }, q);
#pragma unroll
      for (int tau = 0; tau < 4; ++tau)
#pragma unroll
        for (int i = 0; i < 16; ++i) mTs[j][tau * 16 + i] = q[tau][i];
    }
    const int t = j;
    if (t < 64) Zr[t] = (t == 0) ? 1.f : 0.f;
    if (t == 0) logZt[s * QROWS] = 0.f;
    float off = 0.f;
    __syncthreads();
    for (int ch = 0; ch < NCH; ++ch) {
      float acc = 0.f, mx = 0.f;
      if (t < 64) {
#pragma unroll 8
        for (int jj = 0; jj < 64; ++jj) acc = fmaf(mTs[jj][t], Zr[jj], acc);
        logZt[s * QROWS + ch * 64 + 1 + t] = logf(acc) + off;
        mx = acc;
#pragma unroll
        for (int o = 32; o; o >>= 1) mx = fmaxf(mx, __shfl_xor(mx, o));
      }
      __syncthreads();
      if (t < 64) {
        Zr[63 - t] = acc / mx;
        off += logf(mx);
      }
      __syncthreads();
    }
  }
}

// KB merged: blocks 0..127 = k5a_basis; blocks 128..383 = k2c (prefix fixup).
// Phase 0 now uses the logsumexp identity: pi[t][l] = exp(lw[l] + logZ[t-l]
// - logZ[t+1]) — logZ[t+1] IS the logsumexp of that row (reference computes
// softmax and logsumexp of the same loga). This deletes the per-tt 12-deep
// dependent __shfl_xor chains (ds_swizzle lgkm latency ~100cyc each) that
// R10-R12's data-path rewrites never touched.
__global__ __launch_bounds__(128) void kb_basis_fix(
    const float* __restrict__ logw, const float* __restrict__ logZt,
    float* __restrict__ pig, float* __restrict__ rt, float* __restrict__ ctT,
    float* __restrict__ klocal, float* __restrict__ Q,
    const float* __restrict__ S2) {
  // sbuf: [0,4096) psd (pi [t][l]); [4096,8192) Pts (Pt [t][t']);
  //       [8192,16384) Dl ([t][u], u=0..127). After the scan, Rl (stride 65)
  //       aliases [0,8192).
  __shared__ __align__(16) float sbuf[16384];  // 64 KB
  __shared__ float lzs[128];  // LOG2E * logZ[ch*64-63+i], i=0..127
  __shared__ float lws[64];   // LOG2E * logw
  __shared__ float4 gsum[4][32];
  float* psd = sbuf;
  float* Pts = sbuf + 4096;
  float* Dl = sbuf + 8192;
  float* Rl = sbuf;  // stride 65, valid after scan barrier
  const int x = blockIdx.x;
  const int tid = threadIdx.x;
  if (x < 128) {
    const int s = x >> 5, ch = x & 31;
    {
      int idx = ch * 64 - 63 + tid;  // max ch*64+64 <= 2048, in bounds
      lzs[tid] = (idx >= 0) ? logZt[s * QROWS + idx] * LOG2E_F : -INFINITY;
      if (tid < 64) lws[tid] = logw[s * NLM + tid] * LOG2E_F;
    }
    __syncthreads();
    {
      const int l = tid & 63, wv = tid >> 6;
      const float lw2 = lws[l];
      for (int tt = wv; tt < 64; tt += 2) {
        // la2 - lzn2 <= 0 by construction (logZ[t+1] = logsumexp of row)
        float e2 = lw2 + lzs[tt + 63 - l] - lzs[tt + 64];
        float pv = __builtin_exp2f(e2);
        psd[tt * 64 + l] = pv;
        pig[((long)s * NT + ch * 64 + tt) * NLM + l] = pv;
      }
    }
    __syncthreads();
    // Pt[t][t'] = psd[t][t-t'-1] (t'<t) else 0  (32 elems/thread)
    for (int i = tid; i < 4096; i += 128) {
      int t = i >> 6, tp = i & 63;
      Pts[i] = (tp < t) ? psd[t * 64 + (t - tp - 1)] : 0.f;
    }
    // Dl[t][u]: u<64 identity col u; u>=64 history col j=u-64 (64 elems/thread)
    for (int i = tid; i < 8192; i += 128) {
      int t = i >> 7, u = i & 127;
      float d;
      if (u < 64) {
        d = (t == u) ? 1.f : 0.f;
      } else {
        int l = t + (u - 64);
        d = (l < 64) ? psd[t * 64 + l] : 0.f;
      }
      Dl[i] = d;
    }
    __syncthreads();
    // unified flat forward substitution (single instantiation, both waves)
    float qv[64];
    const float* Dcol = Dl + tid;
#pragma unroll
    for (int t = 0; t < 64; ++t) {
      float a0 = Dcol[t * 128], a1 = 0.f, a2 = 0.f, a3 = 0.f;
#pragma unroll
      for (int qd = 0; qd < 16; ++qd) {
        if (qd * 4 < t) {
          float4 p4 = *(const float4*)&Pts[t * 64 + qd * 4];
          a0 = fmaf(p4.x, qv[4 * qd + 0], a0);
          if (4 * qd + 1 < t) a1 = fmaf(p4.y, qv[4 * qd + 1], a1);
          if (4 * qd + 2 < t) a2 = fmaf(p4.z, qv[4 * qd + 2], a2);
          if (4 * qd + 3 < t) a3 = fmaf(p4.w, qv[4 * qd + 3], a3);
        }
      }
      qv[t] = (a0 + a1) + (a2 + a3);
    }
    __syncthreads();  // psd/Pts dead; Rl may now alias them
    if (tid < 64) {
      const int tp = tid;  // impulse column
      float* rrow = rt + (((long)s * NCH + ch) * 64 + tp) * 64;  // [tp][t]
#pragma unroll
      for (int t4 = 0; t4 < 16; ++t4)
        ((float4*)rrow)[t4] = make_float4(qv[4 * t4], qv[4 * t4 + 1],
                                          qv[4 * t4 + 2], qv[4 * t4 + 3]);
#pragma unroll
      for (int t = 0; t < 64; ++t) Rl[tp * 65 + t] = qv[t];
    } else {
      const int j = tid - 64;  // history lookback j+1
      float* ctb = ctT + ((long)s * NCH + ch) * 4096;  // [t][j]
#pragma unroll
      for (int t = 0; t < 64; ++t) ctb[t * 64 + j] = qv[t];
    }
    __syncthreads();
    if (tid < 64) {  // klocal[t] = sum_tp R[t][tp]
      float acc = 0.f;
#pragma unroll 8
      for (int tp = 0; tp < 64; ++tp) acc += Rl[tp * 65 + tid];
      klocal[((long)s * NCH + ch) * 64 + tid] = acc;
    }
  } else {
    const int y = x - 128;
    const int b = y >> 5, ch = y & 31;
    const int g = tid >> 5, c4 = tid & 31;
    if (ch == 0 && g == 0)
      ((float4*)(Q + (long)(b * QROWS) * NC))[c4] = make_float4(0.f, 0.f, 0.f, 0.f);
    float4 run = make_float4(0.f, 0.f, 0.f, 0.f);
    for (int i = 0; i < ch; ++i) {
      float4 v = ((const float4*)(S2 + (long)(b * NCH + i) * NC))[c4];
      run.x += v.x; run.y += v.y; run.z += v.z; run.w += v.w;
    }
    float4* Q4 = (float4*)(Q + (long)(b * QROWS + ch * 64 + 1) * NC);
    float4 vbuf[16];
#pragma unroll
    for (int i = 0; i < 16; ++i) vbuf[i] = Q4[(g * 16 + i) * 32 + c4];
    {
      float4 gs = make_float4(0.f, 0.f, 0.f, 0.f);
#pragma unroll
      for (int i = 0; i < 16; ++i) {
        gs.x += vbuf[i].x; gs.y += vbuf[i].y; gs.z += vbuf[i].z; gs.w += vbuf[i].w;
      }
      gsum[g][c4] = gs;
    }
    __syncthreads();
    for (int gp = 0; gp < 3; ++gp) {
      if (gp < g) {
        float4 v = gsum[gp][c4];
        run.x += v.x; run.y += v.y; run.z += v.z; run.w += v.w;
      }
    }
#pragma unroll
    for (int i = 0; i < 16; ++i) {
      run.x += vbuf[i].x; run.y += vbuf[i].y; run.z += vbuf[i].z; run.w += vbuf[i].w;
      Q4[(g * 16 + i) * 32 + c4] = run;
    }
  }
}

// K4: e[s,b,ti,c] = 1 - 2 * sum_l pi[s,ti,l] * rcp(exp2(y)+1)
__global__ __launch_bounds__(256) void k4_e(
    const float* __restrict__ Q, const float* __restrict__ pi,
    const float* __restrict__ phib, float* __restrict__ eq) {
  __shared__ float Qw[80][64];                   // 20 KB
  __shared__ __align__(16) float ps[4][16][64];  // 16 KB
  const int b = blockIdx.x;
  const int t0 = blockIdx.y * 16;
  const int half = blockIdx.z;
  const int tid = threadIdx.x;
  for (int i = tid; i < 80 * 64; i += 256) {
    int r = i >> 6, cc = i & 63;
    int tau = t0 - 63 + r;
    Qw[r][cc] = (tau >= 0) ? Q[(b * QROWS + tau) * NC + half * 64 + cc] : 0.f;
  }
  for (int i = tid; i < 1024; i += 256) {  // 1024 float4 = 4 scales x 256
    int s = i >> 8, rem = i & 255;
    ((float4*)ps)[i] = ((const float4*)(pi + ((long)s * NT + t0) * NLM))[rem];
  }
  __syncthreads();
  const int c = tid & 63, tg = tid >> 6;  // tg wave-uniform
  const float pb2 = phib[half * 64 + c] * TWO_LOG2E;
  for (int tt = tg; tt < 16; tt += 4) {
    const int ti = t0 + tt;
    const float Qt = Qw[tt + 64][c];
    float a0 = 0.f, a1 = 0.f, a2 = 0.f, a3 = 0.f;
#pragma unroll
    for (int l = 0; l < 64; l += 4) {
      float v[4];
#pragma unroll
      for (int u = 0; u < 4; ++u) {
        const float cl = TWO_LOG2E / (float)(l + u + 9);  // folded constant
        float y = (Qt - Qw[tt + 63 - (l + u)][c]) * cl + pb2;
        v[u] = rcp_fast(__builtin_exp2f(y) + 1.f);
      }
      float4 w0 = *(const float4*)&ps[0][tt][l];
      float4 w1 = *(const float4*)&ps[1][tt][l];
      float4 w2 = *(const float4*)&ps[2][tt][l];
      float4 w3 = *(const float4*)&ps[3][tt][l];
      a0 = fmaf(w0.x, v[0], a0); a0 = fmaf(w0.y, v[1], a0);
      a0 = fmaf(w0.z, v[2], a0); a0 = fmaf(w0.w, v[3], a0);
      a1 = fmaf(w1.x, v[0], a1); a1 = fmaf(w1.y, v[1], a1);
      a1 = fmaf(w1.z, v[2], a1); a1 = fmaf(w1.w, v[3], a1);
      a2 = fmaf(w2.x, v[0], a2); a2 = fmaf(w2.y, v[1], a2);
      a2 = fmaf(w2.z, v[2], a2); a2 = fmaf(w2.w, v[3], a2);
      a3 = fmaf(w3.x, v[0], a3); a3 = fmaf(w3.y, v[1], a3);
      a3 = fmaf(w3.z, v[2], a3); a3 = fmaf(w3.w, v[3], a3);
    }
    const long base = half * 64 + c;
    eq[((long)(0 * 8 + b) * NT + ti) * NC + base] = fmaf(-2.f, a0, 1.f);
    eq[((long)(1 * 8 + b) * NT + ti) * NC + base] = fmaf(-2.f, a1, 1.f);
    eq[((long)(2 * 8 + b) * NT + ti) * NC + base] = fmaf(-2.f, a2, 1.f);
    eq[((long)(3 * 8 + b) * NT + ti) * NC + base] = fmaf(-2.f, a3, 1.f);
  }
}

// K5a-data: qlocal = R @ e per (s,b,chunk) — tiled GEMM, 8t x 8c per lane.
__global__ __launch_bounds__(128) void k5a_data(const float* __restrict__ rt,
                                                float* __restrict__ eq) {
  __shared__ __align__(16) float rts[4096];    // [tp][t] 16 KB
  __shared__ __align__(16) float es[64][128];  // 32 KB
  const int sb = blockIdx.x;  // s*8+b
  const int s = sb >> 3;
  const int ch = blockIdx.y;
  const int tid = threadIdx.x;
  const float4* rsrc = (const float4*)(rt + ((long)s * NCH + ch) * 4096);
#pragma unroll
  for (int i = 0; i < 8; ++i) ((float4*)rts)[tid + 128 * i] = rsrc[tid + 128 * i];
  float* qb = eq + ((long)sb * NT + ch * 64) * NC;
  const float4* esrc = (const float4*)qb;
#pragma unroll
  for (int i = 0; i < 16; ++i) ((float4*)es)[tid + 128 * i] = esrc[tid + 128 * i];
  __syncthreads();
  const int t0 = (tid >> 4) * 8;  // 8 t-tiles
  const int c0 = (tid & 15) * 8;  // 16 c-tiles
  float acc[8][8];
#pragma unroll
  for (int i = 0; i < 8; ++i)
#pragma unroll
    for (int k = 0; k < 8; ++k) acc[i][k] = 0.f;
  for (int tp = 0; tp < 64; ++tp) {
    if (tp <= t0 + 7) {  // R is lower-triangular
      float4 r0 = *(const float4*)&rts[tp * 64 + t0];
      float4 r1 = *(const float4*)&rts[tp * 64 + t0 + 4];
      float4 e0 = *(const float4*)&es[tp][c0];
      float4 e1 = *(const float4*)&es[tp][c0 + 4];
      float rr[8] = {r0.x, r0.y, r0.z, r0.w, r1.x, r1.y, r1.z, r1.w};
      float ee[8] = {e0.x, e0.y, e0.z, e0.w, e1.x, e1.y, e1.z, e1.w};
#pragma unroll
      for (int i = 0; i < 8; ++i)
#pragma unroll
        for (int k = 0; k < 8; ++k) acc[i][k] = fmaf(rr[i], ee[k], acc[i][k]);
    }
  }
#pragma unroll
  for (int i = 0; i < 8; ++i) {
    float4* dst = (float4*)(qb + (t0 + i) * NC + c0);
    dst[0] = make_float4(acc[i][0], acc[i][1], acc[i][2], acc[i][3]);
    dst[1] = make_float4(acc[i][4], acc[i][5], acc[i][6], acc[i][7]);
  }
}

// K5b: cross-chunk combine, no LDS: history in the wave's own registers via
// v_readlane. 256 q-blocks x 2 waves (shared s -> L1 ctT hits); XCD swizzle
// blockIdx.x % 8 == {2s,2s+1}. Plain loads/stores.
// Blocks 256..259: k cross-chunk combine (per s), wave 0 only.
__global__ __launch_bounds__(128) void k5b_scan(const float* __restrict__ ctT,
                                                const float* __restrict__ klocal,
                                                float* __restrict__ eq,
                                                float* __restrict__ kout) {
  const int tid = threadIdx.x;
  const int t = tid & 63;
  if (blockIdx.x < 256) {
    const int e = blockIdx.x & 7, g = blockIdx.x >> 3;
    const int s = e >> 1, hp = e & 1;
    const int b = g & 7, pp = g >> 3;
    const int w = tid >> 6;
    const int sl = ((pp << 1) | hp) * 2 + w;  // 0..15
    const int c0 = sl * 8;
    const int sb = s * 8 + b;
    const float* ctTs = ctT + (long)s * NCH * 4096 + t * 64;
    float* eqb = eq + (long)sb * NT * NC + c0;
    float4 crA[16], crB[16];
    {
      const float4* p = (const float4*)ctTs;
#pragma unroll
      for (int i = 0; i < 16; ++i) crA[i] = p[i];
    }
    float4 qlA0 = ((const float4*)(eqb + t * NC))[0];
    float4 qlA1 = ((const float4*)(eqb + t * NC))[1];
    float4 qlB0, qlB1;
    float hv[8];
#pragma unroll
    for (int i = 0; i < 8; ++i) hv[i] = 0.f;

#define K5B_BODY(CH, CR, QL0, QL1)                                           \
    {                                                                        \
      float acc[8];                                                          \
      _Pragma("unroll") for (int i = 0; i < 8; ++i) acc[i] = 0.f;            \
      const float* cr = (const float*)(CR);                                  \
      _Pragma("unroll") for (int j = 0; j < 64; ++j) {                       \
        float cv = cr[j];                                                    \
        _Pragma("unroll") for (int i = 0; i < 8; ++i)                        \
            acc[i] = fmaf(cv, readlane_f(hv[i], 63 - j), acc[i]);            \
      }                                                                      \
      hv[0] = acc[0] + (QL0).x; hv[1] = acc[1] + (QL0).y;                    \
      hv[2] = acc[2] + (QL0).z; hv[3] = acc[3] + (QL0).w;                    \
      hv[4] = acc[4] + (QL1).x; hv[5] = acc[5] + (QL1).y;                    \
      hv[6] = acc[6] + (QL1).z; hv[7] = acc[7] + (QL1).w;                    \
      float4* qp = (float4*)(eqb + ((CH) * 64 + t) * NC);                    \
      qp[0] = make_float4(hv[0], hv[1], hv[2], hv[3]);                       \
      qp[1] = make_float4(hv[4], hv[5], hv[6], hv[7]);                       \
    }

#pragma unroll 1
    for (int ch = 0; ch < NCH; ch += 2) {
      {
        const float4* p = (const float4*)(ctTs + (ch + 1) * 4096);
#pragma unroll
        for (int i = 0; i < 16; ++i) crB[i] = p[i];
        const float4* qn = (const float4*)(eqb + ((ch + 1) * 64 + t) * NC);
        qlB0 = qn[0];
        qlB1 = qn[1];
      }
      K5B_BODY(ch, crA, qlA0, qlA1)
      if (ch + 2 < NCH) {
        const float4* p = (const float4*)(ctTs + (ch + 2) * 4096);
#pragma unroll
        for (int i = 0; i < 16; ++i) crA[i] = p[i];
        const float4* qn = (const float4*)(eqb + ((ch + 2) * 64 + t) * NC);
        qlA0 = qn[0];
        qlA1 = qn[1];
      }
      K5B_BODY(ch + 1, crB, qlB0, qlB1)
    }
#undef K5B_BODY
  } else if (tid < 64) {
    const int s = blockIdx.x - 256;
    const float* ctTs = ctT + (long)s * NCH * 4096 + t * 64;
    const float* klb = klocal + (long)s * NCH * 64 + t;
    float4 crA[16], crB[16];
    {
      const float4* p = (const float4*)ctTs;
#pragma unroll
      for (int i = 0; i < 16; ++i) crA[i] = p[i];
    }
    float klA = klb[0], klB;
    float hk = 0.f;

#define K5BK_BODY(CH, CR, KL)                                                \
    {                                                                        \
      float acc = (KL);                                                      \
      const float* cr = (const float*)(CR);                                  \
      _Pragma("unroll") for (int j = 0; j < 64; ++j)                         \
          acc = fmaf(cr[j], readlane_f(hk, 63 - j), acc);                    \
      kout[s * NT + (CH) * 64 + t] = acc;                                    \
      hk = acc;                                                              \
    }

#pragma unroll 1
    for (int ch = 0; ch < NCH; ch += 2) {
      {
        const float4* p = (const float4*)(ctTs + (ch + 1) * 4096);
#pragma unroll
        for (int i = 0; i < 16; ++i) crB[i] = p[i];
        klB = klb[(ch + 1) * 64];
      }
      K5BK_BODY(ch, crA, klA)
      if (ch + 2 < NCH) {
        const float4* p = (const float4*)(ctTs + (ch + 2) * 4096);
#pragma unroll
        for (int i = 0; i < 16; ++i) crA[i] = p[i];
        klA = klb[(ch + 2) * 64];
      }
      K5BK_BODY(ch + 1, crB, klB)
    }
#undef K5BK_BODY
  }
}

// K6: rep = (q + 16*anchor)/(k+16) * (k/(k+16)); out = rep_flat @ mix_w + mix_b
__global__ __launch_bounds__(256) void k6_mix(
    const float* __restrict__ q, const float* __restrict__ kout,
    const float* __restrict__ anchor, const float* __restrict__ mixw,
    const float* __restrict__ mixb, float* __restrict__ out) {
  __shared__ __align__(16) float rsdata[16][512];  // 32 KB
  const int b = blockIdx.x;
  const int t0 = blockIdx.y * 16;
  const int tid = threadIdx.x;
  for (int i = tid; i < 16 * 512; i += 256) {
    int r = i >> 9, sc = i & 511;
    int s = sc >> 7, c = sc & 127;
    int ti = t0 + r;
    float qv = q[((long)(s * 8 + b) * NT + ti) * NC + c];
    float kv = kout[s * NT + ti];
    float d1 = rcp_fast(kv + 16.f);
    rsdata[r][sc] = (qv + 16.f * anchor[sc]) * d1 * (kv * d1);
  }
  __syncthreads();
  const int co = tid & 127, hf = tid >> 7;
  const int r0 = hf * 8;
  float mb = mixb[co];
  float acc[8];
#pragma unroll
  for (int r = 0; r < 8; ++r) acc[r] = mb;
  for (int kk = 0; kk < 512; kk += 4) {
    float wa = mixw[(kk + 0) * 128 + co];
    float wb = mixw[(kk + 1) * 128 + co];
    float wc = mixw[(kk + 2) * 128 + co];
    float wd = mixw[(kk + 3) * 128 + co];
#pragma unroll
    for (int r = 0; r < 8; ++r) {
      float4 rv = *(const float4*)&rsdata[r0 + r][kk];
      acc[r] = fmaf(rv.x, wa, acc[r]);
      acc[r] = fmaf(rv.y, wb, acc[r]);
      acc[r] = fmaf(rv.z, wc, acc[r]);
      acc[r] = fmaf(rv.w, wd, acc[r]);
    }
  }
#pragma unroll
  for (int r = 0; r < 8; ++r)
    out[((long)b * NT + t0 + r0 + r) * NC + co] = acc[r];
}

extern "C" void kernel_launch(void* const* d_in, const int* in_sizes, int n_in,
                              void* d_out, int out_size, void* d_ws, size_t ws_size,
                              hipStream_t stream) {
  const float* x = (const float*)d_in[0];
  const float* W = (const float*)d_in[1];
  const float* bias = (const float*)d_in[2];
  const float* phiw = (const float*)d_in[3];
  const float* phib = (const float*)d_in[4];
  const float* anchor = (const float*)d_in[5];
  const float* logw = (const float*)d_in[6];
  const float* mixw = (const float*)d_in[7];
  const float* mixb = (const float*)d_in[8];
  float* out = (float*)d_out;

  float* ws = (float*)d_ws;
  float* Q = ws;                                     // 8*2049*128 = 2,098,176
  float* pi = Q + (long)NB * QROWS * NC;             // 4*2048*64  =   524,288
  float* eq = pi + (long)NS * NT * NLM;              // 32*2048*128= 8,388,608
  float* coefTT = eq + (long)NS * NB * NT * NC;      //               524,288
  float* rtb = coefTT + (long)NS * NCH * 4096;       //               524,288
  float* klocal = rtb + (long)NS * NCH * 4096;       //                 8,192
  float* kout = klocal + (long)NS * NCH * 64;        //                 8,192
  float* logZt = kout + (long)NS * NT;               //                 8,196
  float* S2 = logZt + (long)NS * QROWS;              //                32,768

  hipLaunchKernelGGL(k1_uv, dim3(NB * NT / 16), dim3(128), 0, stream, x, W, bias, phiw, Q);
  hipLaunchKernelGGL(k23_sums_logz, dim3(260), dim3(128), 0, stream, Q, S2, logw, logZt);
  hipLaunchKernelGGL(kb_basis_fix, dim3(384), dim3(128), 0, stream, logw, logZt, pi, rtb, coefTT, klocal, Q, S2);
  hipLaunchKernelGGL(k4_e, dim3(NB, NT / 16, 2), dim3(256), 0, stream, Q, pi, phib, eq);
  hipLaunchKernelGGL(k5a_data, dim3(NS * NB, NCH), dim3(128), 0, stream, rtb, eq);
  hipLaunchKernelGGL(k5b_scan, dim3(260), dim3(128), 0, stream, coefTT, klocal, eq, kout);
  hipLaunchKernelGGL(k6_mix, dim3(NB, NT / 16), dim3(256), 0, stream, eq, kout, anchor, mixw, mixb, out);
}